// Round 3
// baseline (708.181 us; speedup 1.0000x reference)
//
#include <hip/hip_runtime.h>

// LightGCN-style 3-layer bipartite propagation.
// R8: SpMM stuck at ~153us/dispatch, FETCH 496MB = gather L2-miss traffic
// (random source order; working set = whole table > 4MB per-XCD L2).
// Fix: SOURCE-SORTED pair lists. stage_i is col-bucket-grouped, stage_u is
// row-bucket-grouped (free from pass 1); a second multisplit of the
// OPPOSITE-side stage stream into dst buckets yields pairs_u with within-row
// col order (and pairs_i with within-col row order) at 256-granularity.
// Concurrent waves then sweep the source table in tandem -> L2-resident band.
// Stage entries repacked: .x = final pairs word, .y = cross-side dst key.
// Cross-chain buffers (stage2/hist2/offs2) alias uA..iB (dead until SpMM).
// R7's deferred-sum + packed 4B pairs + 8-wide unroll kept. REQ ~164MB.

#define NUM_USERS 100000
#define NUM_ITEMS 50000
#define EMBED_DIM 128
#define NNZ_COUNT 2000000
#define NBUCK_U 391            // ceil(100000/256)
#define NBUCK_I 196            // ceil(50000/256)
#define EPB 8192               // edges per multisplit block
#define NBLK 245               // ceil(NNZ_COUNT/EPB)

// ---------------- bf16 helpers (manual RTNE) ----------------

__device__ __forceinline__ unsigned bf16_rnd(float f) {
    unsigned u = __float_as_uint(f);
    return (u + 0x7FFFu + ((u >> 16) & 1u)) >> 16;
}
__device__ __forceinline__ unsigned pack_bf16(float x, float y) {
    return bf16_rnd(x) | (bf16_rnd(y) << 16);
}

// Both embedding tables in one launch.
__global__ __launch_bounds__(256) void to_bf16_dual(
    const float* __restrict__ a, unsigned* __restrict__ oa, int na8,
    const float* __restrict__ b, unsigned* __restrict__ ob, int nb8)
{
    int i = blockIdx.x * 256 + threadIdx.x;
    const float4* s4; uint4* d4;
    if (i < na8) {
        s4 = reinterpret_cast<const float4*>(a) + i * 2;
        d4 = reinterpret_cast<uint4*>(oa) + i;
    } else {
        i -= na8;
        if (i >= nb8) return;
        s4 = reinterpret_cast<const float4*>(b) + i * 2;
        d4 = reinterpret_cast<uint4*>(ob) + i;
    }
    float4 x = s4[0], y = s4[1];
    uint4 r;
    r.x = pack_bf16(x.x, x.y); r.y = pack_bf16(x.z, x.w);
    r.z = pack_bf16(y.x, y.y); r.w = pack_bf16(y.z, y.w);
    *d4 = r;
}

// ---------------- pass 1: LDS-aggregated multisplit ----------------

__global__ __launch_bounds__(256) void msplit_hist(
    const int* __restrict__ rows, const int* __restrict__ cols,
    int* __restrict__ hist_u, int* __restrict__ hist_i)
{
    __shared__ int h[NBUCK_U + NBUCK_I];
    for (int i = threadIdx.x; i < NBUCK_U + NBUCK_I; i += 256) h[i] = 0;
    __syncthreads();
    const int base = blockIdx.x * EPB;
    const int end = min(base + EPB, NNZ_COUNT);
    for (int e = base + threadIdx.x; e < end; e += 256) {
        atomicAdd(&h[rows[e] >> 8], 1);
        atomicAdd(&h[NBUCK_U + (cols[e] >> 8)], 1);
    }
    __syncthreads();
    for (int b = threadIdx.x; b < NBUCK_U; b += 256)
        hist_u[b * NBLK + blockIdx.x] = h[b];
    for (int b = threadIdx.x; b < NBUCK_I; b += 256)
        hist_i[b * NBLK + blockIdx.x] = h[NBUCK_U + b];
}

// One block per bucket: exclusive scan over its NBLK counts (bucket-relative)
// + emit the bucket total for the cross-bucket scan.
__global__ __launch_bounds__(256) void msplit_offsets(
    const int* __restrict__ hist_u, const int* __restrict__ hist_i,
    int* __restrict__ offs_u, int* __restrict__ offs_i,
    int* __restrict__ tot_u, int* __restrict__ tot_i)
{
    __shared__ int buf[256];
    int b = blockIdx.x;
    const int* hist; int* offs; int* tot; int nbuck;
    if (b < NBUCK_U) { hist = hist_u; offs = offs_u; tot = tot_u; nbuck = NBUCK_U; }
    else { b -= NBUCK_U; hist = hist_i; offs = offs_i; tot = tot_i; nbuck = NBUCK_I; }
    const int t = threadIdx.x;
    const int x = (t < NBLK) ? hist[b * NBLK + t] : 0;
    buf[t] = x;
    __syncthreads();
    for (int d = 1; d < 256; d <<= 1) {
        const int y = (t >= d) ? buf[t - d] : 0;
        __syncthreads();
        buf[t] += y;
        __syncthreads();
    }
    if (t < NBLK) offs[t * nbuck + b] = buf[t] - x;   // bucket-relative
    if (t == 255) tot[b] = buf[255];                  // bucket total
}

// Cross-bucket exclusive scan (block 0 = users, 1 = items).
__global__ __launch_bounds__(512) void scan_buckets(
    const int* __restrict__ tot_u, int* __restrict__ bbase_u,
    const int* __restrict__ tot_i, int* __restrict__ bbase_i)
{
    __shared__ int buf[512];
    const int t = threadIdx.x;
    const int* tot; int* bbase; int nb;
    if (blockIdx.x == 0) { tot = tot_u; bbase = bbase_u; nb = NBUCK_U; }
    else                 { tot = tot_i; bbase = bbase_i; nb = NBUCK_I; }
    const int v = (t < nb) ? tot[t] : 0;
    buf[t] = v;
    __syncthreads();
    for (int d = 1; d < 512; d <<= 1) {
        const int y = (t >= d) ? buf[t - d] : 0;
        __syncthreads();
        buf[t] += y;
        __syncthreads();
    }
    if (t <= nb) bbase[t] = buf[t] - v;   // exclusive; bbase[nb] = total
}

// Scatter into bucket-contiguous runs. NEW packing:
//   stage_u (by row bucket): .x = row(17)|vb15<<17 (= final pairs_i word), .y = col
//   stage_i (by col bucket): .x = col(16)|vb16<<16 (= final pairs_u word), .y = row
__global__ __launch_bounds__(256) void msplit_scatter(
    const int* __restrict__ rows, const int* __restrict__ cols,
    const float* __restrict__ vals,
    const int* __restrict__ offs_u, const int* __restrict__ offs_i,
    const int* __restrict__ bbase_u, const int* __restrict__ bbase_i,
    int2* __restrict__ stage_u, int2* __restrict__ stage_i)
{
    __shared__ int cu[NBUCK_U];
    __shared__ int ci[NBUCK_I];
    const int t = threadIdx.x;
    for (int b = t; b < NBUCK_U; b += 256)
        cu[b] = offs_u[blockIdx.x * NBUCK_U + b] + bbase_u[b];
    for (int b = t; b < NBUCK_I; b += 256)
        ci[b] = offs_i[blockIdx.x * NBUCK_I + b] + bbase_i[b];
    __syncthreads();
    const int base = blockIdx.x * EPB;
    const int end = min(base + EPB, NNZ_COUNT);
    for (int e = base + t; e < end; e += 256) {
        const int r = rows[e];
        const int c = cols[e];
        const unsigned vb = bf16_rnd(vals[e]);
        const int su = atomicAdd(&cu[r >> 8], 1);
        stage_u[su] = make_int2((int)((unsigned)r | ((vb & 0x7FFFu) << 17)), c);
        const int si = atomicAdd(&ci[c >> 8], 1);
        stage_i[si] = make_int2((int)((unsigned)c | (vb << 16)), r);
    }
}

// ---------------- pass 2: cross multisplit (source-sorted pairs) ----------
// u-chain input = stage_i (col-ordered stream), dst key = .y = row.
// i-chain input = stage_u (row-ordered stream), dst key = .y = col.

__global__ __launch_bounds__(256) void hist2_dual(
    const int2* __restrict__ stage_i, const int2* __restrict__ stage_u,
    int* __restrict__ h2_u, int* __restrict__ h2_i)
{
    __shared__ int h[NBUCK_U];
    const bool uchain = (blockIdx.x < NBLK);
    const int blk = uchain ? blockIdx.x : blockIdx.x - NBLK;
    const int2* stage = uchain ? stage_i : stage_u;
    int* h2 = uchain ? h2_u : h2_i;
    const int nbuck = uchain ? NBUCK_U : NBUCK_I;
    for (int i = threadIdx.x; i < nbuck; i += 256) h[i] = 0;
    __syncthreads();
    const int base = blk * EPB;
    const int end = min(base + EPB, NNZ_COUNT);
    for (int e = base + threadIdx.x; e < end; e += 256)
        atomicAdd(&h[stage[e].y >> 8], 1);
    __syncthreads();
    for (int b = threadIdx.x; b < nbuck; b += 256)
        h2[b * NBLK + blk] = h[b];
}

// Per-bucket scan over chunk counts; folds in the (already-known) bucket base.
__global__ __launch_bounds__(256) void offsets2_dual(
    const int* __restrict__ h2_u, const int* __restrict__ h2_i,
    const int* __restrict__ bbase_u, const int* __restrict__ bbase_i,
    int* __restrict__ o2_u, int* __restrict__ o2_i)
{
    __shared__ int buf[256];
    int b = blockIdx.x;
    const int* h2; const int* bbase; int* o2; int nbuck;
    if (b < NBUCK_U) { h2 = h2_u; bbase = bbase_u; o2 = o2_u; nbuck = NBUCK_U; }
    else { b -= NBUCK_U; h2 = h2_i; bbase = bbase_i; o2 = o2_i; nbuck = NBUCK_I; }
    const int t = threadIdx.x;
    const int x = (t < NBLK) ? h2[b * NBLK + t] : 0;
    buf[t] = x;
    __syncthreads();
    for (int d = 1; d < 256; d <<= 1) {
        const int y = (t >= d) ? buf[t - d] : 0;
        __syncthreads();
        buf[t] += y;
        __syncthreads();
    }
    if (t < NBLK) o2[t * nbuck + b] = bbase[b] + buf[t] - x;
}

// Stable-by-chunk scatter of the opposite-side stream into dst buckets.
__global__ __launch_bounds__(256) void scatter2_dual(
    const int2* __restrict__ stage_i, const int2* __restrict__ stage_u,
    const int* __restrict__ o2_u, const int* __restrict__ o2_i,
    int2* __restrict__ stage2_u, int2* __restrict__ stage2_i)
{
    __shared__ int cur[NBUCK_U];
    const bool uchain = (blockIdx.x < NBLK);
    const int blk = uchain ? blockIdx.x : blockIdx.x - NBLK;
    const int2* stage = uchain ? stage_i : stage_u;
    const int* o2 = uchain ? o2_u : o2_i;
    int2* stage2 = uchain ? stage2_u : stage2_i;
    const int nbuck = uchain ? NBUCK_U : NBUCK_I;
    const int t = threadIdx.x;
    for (int b = t; b < nbuck; b += 256) cur[b] = o2[blk * nbuck + b];
    __syncthreads();
    const int base = blk * EPB;
    const int end = min(base + EPB, NNZ_COUNT);
    for (int e = base + t; e < end; e += 256) {
        const int2 s = stage[e];
        const int slot = atomicAdd(&cur[s.y >> 8], 1);
        stage2[slot] = s;
    }
}

// Per-bucket: LDS histogram of 256 local dst rows -> scan -> ptr[] inline ->
// LDS-cursor scatter; .x is already the final pairs word.
__global__ __launch_bounds__(256) void build_dual(
    const int* __restrict__ bbase_u, const int2* __restrict__ stage2_u,
    unsigned* __restrict__ pairs_u, int* __restrict__ ptr_u,
    const int* __restrict__ bbase_i, const int2* __restrict__ stage2_i,
    unsigned* __restrict__ pairs_i, int* __restrict__ ptr_i)
{
    __shared__ int hcnt[256];
    __shared__ int buf[256];
    __shared__ int cur[256];
    const int t = threadIdx.x;
    int b = blockIdx.x;
    const bool uside = (b < NBUCK_U);
    const int* bbase; const int2* stage2; unsigned* pairs; int* ptr; int n;
    if (uside) { bbase = bbase_u; stage2 = stage2_u; pairs = pairs_u; ptr = ptr_u; n = NUM_USERS; }
    else { b -= NBUCK_U; bbase = bbase_i; stage2 = stage2_i; pairs = pairs_i; ptr = ptr_i; n = NUM_ITEMS; }
    const int beg = bbase[b];
    const int end = bbase[b + 1];

    hcnt[t] = 0;
    __syncthreads();
    for (int idx = beg + t; idx < end; idx += 256)
        atomicAdd(&hcnt[stage2[idx].y & 255], 1);
    __syncthreads();

    const int v = hcnt[t];
    buf[t] = v;
    __syncthreads();
    for (int d = 1; d < 256; d <<= 1) {
        const int y = (t >= d) ? buf[t - d] : 0;
        __syncthreads();
        buf[t] += y;
        __syncthreads();
    }
    const int rowbase = beg + buf[t] - v;
    cur[t] = rowbase;
    const int first = b << 8;
    if (first + t < n) ptr[first + t] = rowbase;
    if (first + t == n) ptr[n] = end;                       // partial last bucket
    else if (first + 256 == n && t == 0) ptr[n] = end;      // exact-fit last bucket
    __syncthreads();

    for (int idx = beg + t; idx < end; idx += 256) {
        const int2 s = stage2[idx];
        const int slot = atomicAdd(&cur[s.y & 255], 1);
        pairs[slot] = (unsigned)s.x;
    }
}

// ---------------- SpMM: one 64-lane wave per destination row ----------------

template<bool USIDE>
__device__ __forceinline__ void decode_pair(unsigned s, int& c, float& v) {
    if (USIDE) { c = (int)(s & 0xFFFFu);  v = __uint_as_float(s & 0xFFFF0000u); }
    else       { c = (int)(s & 0x1FFFFu); v = __uint_as_float((s & 0xFFFE0000u) >> 1); }
}

// MODE 0: write bf16 dst only. MODE 1: out = (base + l1 + l2 + acc) * 0.25.
template<int MODE, bool USIDE>
__device__ __forceinline__ void spmm_row_bf(
    const int* __restrict__ ptr, const unsigned* __restrict__ pairs,
    const unsigned* __restrict__ src, unsigned* __restrict__ dst,
    const unsigned* __restrict__ l1, const unsigned* __restrict__ l2,
    const float* __restrict__ base, float* __restrict__ out,
    int row, int lane)
{
    const int start = ptr[row];
    const int end   = ptr[row + 1];
    float2 acc = make_float2(0.f, 0.f);

    for (int chunk = start; chunk < end; chunk += 64) {
        const int idx = chunk + lane;
        const unsigned p = (idx < end) ? pairs[idx] : 0u;
        int m = end - chunk; if (m > 64) m = 64;

        int j = 0;
        for (; j + 8 <= m; j += 8) {
            unsigned sv[8]; int c[8]; float v[8]; unsigned g[8];
            #pragma unroll
            for (int k = 0; k < 8; ++k) sv[k] = (unsigned)__shfl((int)p, j + k);
            #pragma unroll
            for (int k = 0; k < 8; ++k) {
                decode_pair<USIDE>(sv[k], c[k], v[k]);
                g[k] = src[(size_t)c[k] * 64 + lane];
            }
            #pragma unroll
            for (int k = 0; k < 8; ++k) {
                acc.x += v[k] * __uint_as_float(g[k] << 16);
                acc.y += v[k] * __uint_as_float(g[k] & 0xFFFF0000u);
            }
        }
        for (; j < m; ++j) {
            const unsigned s = (unsigned)__shfl((int)p, j);
            int c; float v;
            decode_pair<USIDE>(s, c, v);
            const unsigned g = src[(size_t)c * 64 + lane];
            acc.x += v * __uint_as_float(g << 16);
            acc.y += v * __uint_as_float(g & 0xFFFF0000u);
        }
    }

    if (MODE == 0) {
        dst[(size_t)row * 64 + lane] = pack_bf16(acc.x, acc.y);
    } else {
        const unsigned a1 = l1[(size_t)row * 64 + lane];
        const unsigned a2 = l2[(size_t)row * 64 + lane];
        const size_t o = (size_t)row * EMBED_DIM + (lane << 1);
        const float2 bs = *reinterpret_cast<const float2*>(base + o);
        float2 r;
        r.x = (bs.x + __uint_as_float(a1 << 16) + __uint_as_float(a2 << 16) + acc.x) * 0.25f;
        r.y = (bs.y + __uint_as_float(a1 & 0xFFFF0000u) + __uint_as_float(a2 & 0xFFFF0000u) + acc.y) * 0.25f;
        *reinterpret_cast<float2*>(out + o) = r;
    }
}

template<int MODE>
__global__ __launch_bounds__(256) void csr_spmm_dual_bf(
    const int* __restrict__ ptr_u, const unsigned* __restrict__ pairs_u,
    const unsigned* __restrict__ src_u, unsigned* __restrict__ dst_u,
    const unsigned* __restrict__ l1_u, const unsigned* __restrict__ l2_u,
    const float* __restrict__ base_u, float* __restrict__ out_u,
    const int* __restrict__ ptr_i, const unsigned* __restrict__ pairs_i,
    const unsigned* __restrict__ src_i, unsigned* __restrict__ dst_i,
    const unsigned* __restrict__ l1_i, const unsigned* __restrict__ l2_i,
    const float* __restrict__ base_i, float* __restrict__ out_i,
    int GU)
{
    const int lane = threadIdx.x & 63;
    const int w = threadIdx.x >> 6;
    if ((int)blockIdx.x < GU) {
        const int row = blockIdx.x * 4 + w;
        if (row < NUM_USERS)
            spmm_row_bf<MODE, true>(ptr_u, pairs_u, src_u, dst_u, l1_u, l2_u, base_u, out_u, row, lane);
    } else {
        const int row = ((int)blockIdx.x - GU) * 4 + w;
        if (row < NUM_ITEMS)
            spmm_row_bf<MODE, false>(ptr_i, pairs_i, src_i, dst_i, l1_i, l2_i, base_i, out_i, row, lane);
    }
}

// ---------------- fallback (round-1 atomic path) ----------------

__global__ __launch_bounds__(256) void edge_spmm(
    const float* __restrict__ vals, const int* __restrict__ rows,
    const int* __restrict__ cols, const float* __restrict__ u_src,
    const float* __restrict__ i_src, float* __restrict__ u_dst,
    float* __restrict__ i_dst, int nnz)
{
    const int lane = threadIdx.x & 31;
    const int e = blockIdx.x * 8 + (threadIdx.x >> 5);
    if (e >= nnz) return;
    const float v = vals[e];
    const size_t ro = (size_t)rows[e] * EMBED_DIM + lane * 4;
    const size_t co = (size_t)cols[e] * EMBED_DIM + lane * 4;
    const float4 iv = *reinterpret_cast<const float4*>(i_src + co);
    const float4 uv = *reinterpret_cast<const float4*>(u_src + ro);
    atomicAdd(u_dst + ro + 0, v * iv.x); atomicAdd(u_dst + ro + 1, v * iv.y);
    atomicAdd(u_dst + ro + 2, v * iv.z); atomicAdd(u_dst + ro + 3, v * iv.w);
    atomicAdd(i_dst + co + 0, v * uv.x); atomicAdd(i_dst + co + 1, v * uv.y);
    atomicAdd(i_dst + co + 2, v * uv.z); atomicAdd(i_dst + co + 3, v * uv.w);
}

__global__ __launch_bounds__(256) void acc_scale(
    float* __restrict__ out, const float* __restrict__ x, long n, float scale)
{
    long i = ((long)blockIdx.x * blockDim.x + threadIdx.x) * 4;
    if (i >= n) return;
    float4 o = *reinterpret_cast<float4*>(out + i);
    float4 a = *reinterpret_cast<const float4*>(x + i);
    o.x = (o.x + a.x) * scale; o.y = (o.y + a.y) * scale;
    o.z = (o.z + a.z) * scale; o.w = (o.w + a.w) * scale;
    *reinterpret_cast<float4*>(out + i) = o;
}

// ---------------- launch ----------------

extern "C" void kernel_launch(void* const* d_in, const int* in_sizes, int n_in,
                              void* d_out, int out_size, void* d_ws, size_t ws_size,
                              hipStream_t stream)
{
    const float* user = (const float*)d_in[0];
    const float* item = (const float*)d_in[1];
    const float* vals = (const float*)d_in[2];
    const int*   rows = (const int*)d_in[3];
    const int*   cols = (const int*)d_in[4];

    const size_t UD = (size_t)NUM_USERS * EMBED_DIM;   // 12.8M
    const size_t ID = (size_t)NUM_ITEMS * EMBED_DIM;   //  6.4M

    float* out_u = (float*)d_out;
    float* out_i = out_u + UD;

    // ---- CSR-path workspace layout ----
    char* ws = (char*)d_ws;
    unsigned* user_bf = (unsigned*)ws;              ws += UD * 2;
    unsigned* item_bf = (unsigned*)ws;              ws += ID * 2;
    unsigned* uA = (unsigned*)ws;                   ws += UD * 2;   // uA..iB: 76.8MB contiguous
    unsigned* uB = (unsigned*)ws;                   ws += UD * 2;
    unsigned* iA = (unsigned*)ws;                   ws += ID * 2;
    unsigned* iB = (unsigned*)ws;                   ws += ID * 2;
    unsigned* pairs_u = (unsigned*)ws;              ws += (size_t)NNZ_COUNT * 4;
    unsigned* pairs_i = (unsigned*)ws;              ws += (size_t)NNZ_COUNT * 4;
    int2* stage_u = (int2*)ws;                      ws += (size_t)NNZ_COUNT * 8;
    int2* stage_i = (int2*)ws;                      ws += (size_t)NNZ_COUNT * 8;
    int* ptr_u = (int*)ws;                          ws += (NUM_USERS + 1) * 4;
    int* ptr_i = (int*)ws;                          ws += (NUM_ITEMS + 1) * 4;
    int* bbase_u = (int*)ws;                        ws += (NBUCK_U + 1) * 4;
    int* bbase_i = (int*)ws;                        ws += (NBUCK_I + 1) * 4;
    const size_t REQ = (size_t)(ws - (char*)d_ws);  // ~164 MB

    // Pass-1 hist/offs/tot (~1.16 MB) alias into pairs_u (consumed by
    // msplit_scatter before build_dual writes pairs_u).
    int* hist_u = (int*)pairs_u;
    int* hist_i = hist_u + NBUCK_U * NBLK;
    int* offs_u = hist_i + NBUCK_I * NBLK;
    int* offs_i = offs_u + NBLK * NBUCK_U;
    int* tot_u  = offs_i + NBLK * NBUCK_I;
    int* tot_i  = tot_u + NBUCK_U;

    // Pass-2 buffers alias uA..iB (dead until SpMM layer 1): stage2_u (16MB),
    // stage2_i (16MB), then h2/o2 (~1.15MB) — total 33.2MB < 76.8MB.
    char* mid = (char*)uA;
    int2* stage2_u = (int2*)mid;
    int2* stage2_i = (int2*)(mid + (size_t)NNZ_COUNT * 8);
    int* h2_u = (int*)(mid + (size_t)NNZ_COUNT * 16);
    int* h2_i = h2_u + NBUCK_U * NBLK;
    int* o2_u = h2_i + NBUCK_I * NBLK;
    int* o2_i = o2_u + NBLK * NBUCK_U;

    if (ws_size >= REQ) {
        // ---- prep: bf16 copies of the input tables ----
        const int NA8 = (int)(UD / 8), NB8 = (int)(ID / 8);
        to_bf16_dual<<<(NA8 + NB8 + 255) / 256, 256, 0, stream>>>(
            user, user_bf, NA8, item, item_bf, NB8);

        // ---- pass 1: bucket-grouped stages (atomic-free) ----
        msplit_hist<<<NBLK, 256, 0, stream>>>(rows, cols, hist_u, hist_i);
        msplit_offsets<<<NBUCK_U + NBUCK_I, 256, 0, stream>>>(
            hist_u, hist_i, offs_u, offs_i, tot_u, tot_i);
        scan_buckets<<<2, 512, 0, stream>>>(tot_u, bbase_u, tot_i, bbase_i);
        msplit_scatter<<<NBLK, 256, 0, stream>>>(
            rows, cols, vals, offs_u, offs_i, bbase_u, bbase_i, stage_u, stage_i);

        // ---- pass 2: cross multisplit -> source-sorted pairs ----
        hist2_dual<<<2 * NBLK, 256, 0, stream>>>(stage_i, stage_u, h2_u, h2_i);
        offsets2_dual<<<NBUCK_U + NBUCK_I, 256, 0, stream>>>(
            h2_u, h2_i, bbase_u, bbase_i, o2_u, o2_i);
        scatter2_dual<<<2 * NBLK, 256, 0, stream>>>(
            stage_i, stage_u, o2_u, o2_i, stage2_u, stage2_i);
        build_dual<<<NBUCK_U + NBUCK_I, 256, 0, stream>>>(
            bbase_u, stage2_u, pairs_u, ptr_u,
            bbase_i, stage2_i, pairs_i, ptr_i);

        const int GU = (NUM_USERS + 3) / 4;   // 25000
        const int GI = (NUM_ITEMS + 3) / 4;   // 12500

        // layer 1: src = bf16 inputs -> uA/iA (dst only, no sum traffic)
        csr_spmm_dual_bf<0><<<GU + GI, 256, 0, stream>>>(
            ptr_u, pairs_u, item_bf, uA, nullptr, nullptr, nullptr, nullptr,
            ptr_i, pairs_i, user_bf, iA, nullptr, nullptr, nullptr, nullptr, GU);
        // layer 2: src = uA/iA -> uB/iB
        csr_spmm_dual_bf<0><<<GU + GI, 256, 0, stream>>>(
            ptr_u, pairs_u, iA, uB, nullptr, nullptr, nullptr, nullptr,
            ptr_i, pairs_i, uA, iB, nullptr, nullptr, nullptr, nullptr, GU);
        // layer 3: fused epilogue out = (base + l1 + l2 + acc) / 4
        csr_spmm_dual_bf<1><<<GU + GI, 256, 0, stream>>>(
            ptr_u, pairs_u, iB, nullptr, uA, uB, user, out_u,
            ptr_i, pairs_i, uB, nullptr, iA, iB, item, out_i, GU);
    } else {
        // ---- fallback: round-1 atomic path (fp32 buffers carved from ws) ----
        char* fw = (char*)d_ws;
        float* fuA = (float*)fw;                    fw += UD * 4;
        float* fuB = (float*)fw;                    fw += UD * 4;
        float* fiA = (float*)fw;                    fw += ID * 4;
        float* fiB = (float*)fw;                    fw += ID * 4;

        const int EDGE_BLOCKS = (NNZ_COUNT + 7) / 8;
        const int ACC_U = (int)(UD / 1024), ACC_I = (int)(ID / 1024);

        hipMemcpyAsync(out_u, user, UD * 4, hipMemcpyDeviceToDevice, stream);
        hipMemcpyAsync(out_i, item, ID * 4, hipMemcpyDeviceToDevice, stream);

        hipMemsetAsync(fuA, 0, UD * 4, stream);
        hipMemsetAsync(fiA, 0, ID * 4, stream);
        edge_spmm<<<EDGE_BLOCKS, 256, 0, stream>>>(vals, rows, cols, user, item, fuA, fiA, NNZ_COUNT);
        acc_scale<<<ACC_U, 256, 0, stream>>>(out_u, fuA, (long)UD, 1.0f);
        acc_scale<<<ACC_I, 256, 0, stream>>>(out_i, fiA, (long)ID, 1.0f);

        hipMemsetAsync(fuB, 0, UD * 4, stream);
        hipMemsetAsync(fiB, 0, ID * 4, stream);
        edge_spmm<<<EDGE_BLOCKS, 256, 0, stream>>>(vals, rows, cols, fuA, fiA, fuB, fiB, NNZ_COUNT);
        acc_scale<<<ACC_U, 256, 0, stream>>>(out_u, fuB, (long)UD, 1.0f);
        acc_scale<<<ACC_I, 256, 0, stream>>>(out_i, fiB, (long)ID, 1.0f);

        hipMemsetAsync(fuA, 0, UD * 4, stream);
        hipMemsetAsync(fiA, 0, ID * 4, stream);
        edge_spmm<<<EDGE_BLOCKS, 256, 0, stream>>>(vals, rows, cols, fuB, fiB, fuA, fiA, NNZ_COUNT);
        acc_scale<<<ACC_U, 256, 0, stream>>>(out_u, fuA, (long)UD, 0.25f);
        acc_scale<<<ACC_I, 256, 0, stream>>>(out_i, fiA, (long)ID, 0.25f);
    }
}

// Round 4
// 652.074 us; speedup vs baseline: 1.0860x; 1.0860x over previous
//
#include <hip/hip_runtime.h>

// LightGCN-style 3-layer bipartite propagation.
// R9: (a) REVERT R8's cross-multisplit (source-sorting was a no-op: staggered
// block starts spread the sorted bands uniformly over the table, so the
// instantaneous L2 working set never shrank — FETCH was bit-identical).
// (b) SpMM latency fix: pair broadcasts were 8 serialized ds_bpermute per
// batch ahead of every gather burst. start/end are wave-uniform -> pin to
// SGPR via readfirstlane and load pairs[e+k] at uniform addresses (scalar/
// broadcast load, no shfl). Gathers now issue immediately. float2 ext-vector
// accumulator -> v_pk_fma_f32 halves FMA count; lane-base pointer hoisted.
// R7's deferred-sum + packed 4B pairs + atomic-free multisplit build kept.

#define NUM_USERS 100000
#define NUM_ITEMS 50000
#define EMBED_DIM 128
#define NNZ_COUNT 2000000
#define NBUCK_U 391            // ceil(100000/256)
#define NBUCK_I 196            // ceil(50000/256)
#define EPB 8192               // edges per multisplit block
#define NBLK 245               // ceil(NNZ_COUNT/EPB)

typedef float v2f __attribute__((ext_vector_type(2)));

// ---------------- bf16 helpers (manual RTNE) ----------------

__device__ __forceinline__ unsigned bf16_rnd(float f) {
    unsigned u = __float_as_uint(f);
    return (u + 0x7FFFu + ((u >> 16) & 1u)) >> 16;
}
__device__ __forceinline__ unsigned pack_bf16(float x, float y) {
    return bf16_rnd(x) | (bf16_rnd(y) << 16);
}

// Both embedding tables in one launch.
__global__ __launch_bounds__(256) void to_bf16_dual(
    const float* __restrict__ a, unsigned* __restrict__ oa, int na8,
    const float* __restrict__ b, unsigned* __restrict__ ob, int nb8)
{
    int i = blockIdx.x * 256 + threadIdx.x;
    const float4* s4; uint4* d4;
    if (i < na8) {
        s4 = reinterpret_cast<const float4*>(a) + i * 2;
        d4 = reinterpret_cast<uint4*>(oa) + i;
    } else {
        i -= na8;
        if (i >= nb8) return;
        s4 = reinterpret_cast<const float4*>(b) + i * 2;
        d4 = reinterpret_cast<uint4*>(ob) + i;
    }
    float4 x = s4[0], y = s4[1];
    uint4 r;
    r.x = pack_bf16(x.x, x.y); r.y = pack_bf16(x.z, x.w);
    r.z = pack_bf16(y.x, y.y); r.w = pack_bf16(y.z, y.w);
    *d4 = r;
}

// ---------------- LDS-aggregated multisplit (phase A) ----------------

__global__ __launch_bounds__(256) void msplit_hist(
    const int* __restrict__ rows, const int* __restrict__ cols,
    int* __restrict__ hist_u, int* __restrict__ hist_i)
{
    __shared__ int h[NBUCK_U + NBUCK_I];
    for (int i = threadIdx.x; i < NBUCK_U + NBUCK_I; i += 256) h[i] = 0;
    __syncthreads();
    const int base = blockIdx.x * EPB;
    const int end = min(base + EPB, NNZ_COUNT);
    for (int e = base + threadIdx.x; e < end; e += 256) {
        atomicAdd(&h[rows[e] >> 8], 1);
        atomicAdd(&h[NBUCK_U + (cols[e] >> 8)], 1);
    }
    __syncthreads();
    for (int b = threadIdx.x; b < NBUCK_U; b += 256)
        hist_u[b * NBLK + blockIdx.x] = h[b];
    for (int b = threadIdx.x; b < NBUCK_I; b += 256)
        hist_i[b * NBLK + blockIdx.x] = h[NBUCK_U + b];
}

// One block per bucket: exclusive scan over its NBLK counts (bucket-relative)
// + emit the bucket total for the cross-bucket scan.
__global__ __launch_bounds__(256) void msplit_offsets(
    const int* __restrict__ hist_u, const int* __restrict__ hist_i,
    int* __restrict__ offs_u, int* __restrict__ offs_i,
    int* __restrict__ tot_u, int* __restrict__ tot_i)
{
    __shared__ int buf[256];
    int b = blockIdx.x;
    const int* hist; int* offs; int* tot; int nbuck;
    if (b < NBUCK_U) { hist = hist_u; offs = offs_u; tot = tot_u; nbuck = NBUCK_U; }
    else { b -= NBUCK_U; hist = hist_i; offs = offs_i; tot = tot_i; nbuck = NBUCK_I; }
    const int t = threadIdx.x;
    const int x = (t < NBLK) ? hist[b * NBLK + t] : 0;
    buf[t] = x;
    __syncthreads();
    for (int d = 1; d < 256; d <<= 1) {
        const int y = (t >= d) ? buf[t - d] : 0;
        __syncthreads();
        buf[t] += y;
        __syncthreads();
    }
    if (t < NBLK) offs[t * nbuck + b] = buf[t] - x;   // bucket-relative
    if (t == 255) tot[b] = buf[255];                  // bucket total
}

// Cross-bucket exclusive scan (block 0 = users, 1 = items).
__global__ __launch_bounds__(512) void scan_buckets(
    const int* __restrict__ tot_u, int* __restrict__ bbase_u,
    const int* __restrict__ tot_i, int* __restrict__ bbase_i)
{
    __shared__ int buf[512];
    const int t = threadIdx.x;
    const int* tot; int* bbase; int nb;
    if (blockIdx.x == 0) { tot = tot_u; bbase = bbase_u; nb = NBUCK_U; }
    else                 { tot = tot_i; bbase = bbase_i; nb = NBUCK_I; }
    const int v = (t < nb) ? tot[t] : 0;
    buf[t] = v;
    __syncthreads();
    for (int d = 1; d < 512; d <<= 1) {
        const int y = (t >= d) ? buf[t - d] : 0;
        __syncthreads();
        buf[t] += y;
        __syncthreads();
    }
    if (t <= nb) bbase[t] = buf[t] - v;   // exclusive; bbase[nb] = total
}

// Scatter with LDS cursors: writes land in bucket-contiguous runs.
// u stage: col(16b) | local_row(8b)<<16 ; i stage: row(17b) | local_col(8b)<<17.
__global__ __launch_bounds__(256) void msplit_scatter(
    const int* __restrict__ rows, const int* __restrict__ cols,
    const float* __restrict__ vals,
    const int* __restrict__ offs_u, const int* __restrict__ offs_i,
    const int* __restrict__ bbase_u, const int* __restrict__ bbase_i,
    int2* __restrict__ stage_u, int2* __restrict__ stage_i)
{
    __shared__ int cu[NBUCK_U];
    __shared__ int ci[NBUCK_I];
    const int t = threadIdx.x;
    for (int b = t; b < NBUCK_U; b += 256)
        cu[b] = offs_u[blockIdx.x * NBUCK_U + b] + bbase_u[b];
    for (int b = t; b < NBUCK_I; b += 256)
        ci[b] = offs_i[blockIdx.x * NBUCK_I + b] + bbase_i[b];
    __syncthreads();
    const int base = blockIdx.x * EPB;
    const int end = min(base + EPB, NNZ_COUNT);
    for (int e = base + t; e < end; e += 256) {
        const int r = rows[e];
        const int c = cols[e];
        const int vb = __float_as_int(vals[e]);
        const int su = atomicAdd(&cu[r >> 8], 1);
        stage_u[su] = make_int2(c | ((r & 255) << 16), vb);
        const int si = atomicAdd(&ci[c >> 8], 1);
        stage_i[si] = make_int2(r | ((c & 255) << 17), vb);
    }
}

// Phase B: one block per bucket. LDS histogram of the bucket's 256 local
// rows -> LDS scan -> per-row CSR pointers written inline -> LDS-cursor
// scatter into packed 4B pairs:
//   u pair: col(16b) | bf16(val)<<16
//   i pair: row(17b) | (bf16(val)&0x7FFF)<<17   (val >= 0, sign dropped)
__global__ __launch_bounds__(256) void bucket_build(
    const int* __restrict__ bbase_u, const int2* __restrict__ stage_u,
    unsigned* __restrict__ pairs_u, int* __restrict__ ptr_u,
    const int* __restrict__ bbase_i, const int2* __restrict__ stage_i,
    unsigned* __restrict__ pairs_i, int* __restrict__ ptr_i)
{
    __shared__ int hcnt[256];
    __shared__ int buf[256];
    __shared__ int cur[256];
    const int t = threadIdx.x;
    int b = blockIdx.x;
    const bool uside = (b < NBUCK_U);
    const int* bbase; const int2* stage; unsigned* pairs; int* ptr; int n; int sh;
    if (uside) { bbase = bbase_u; stage = stage_u; pairs = pairs_u; ptr = ptr_u; n = NUM_USERS; sh = 16; }
    else { b -= NBUCK_U; bbase = bbase_i; stage = stage_i; pairs = pairs_i; ptr = ptr_i; n = NUM_ITEMS; sh = 17; }
    const int beg = bbase[b];
    const int end = bbase[b + 1];

    hcnt[t] = 0;
    __syncthreads();
    for (int idx = beg + t; idx < end; idx += 256)
        atomicAdd(&hcnt[(stage[idx].x >> sh) & 255], 1);
    __syncthreads();

    const int v = hcnt[t];
    buf[t] = v;
    __syncthreads();
    for (int d = 1; d < 256; d <<= 1) {
        const int y = (t >= d) ? buf[t - d] : 0;
        __syncthreads();
        buf[t] += y;
        __syncthreads();
    }
    const int rowbase = beg + buf[t] - v;   // exclusive scan + bucket base
    cur[t] = rowbase;
    const int first = b << 8;
    if (first + t < n) ptr[first + t] = rowbase;
    if (first + t == n) ptr[n] = end;                       // partial last bucket
    else if (first + 256 == n && t == 0) ptr[n] = end;      // exact-fit last bucket
    __syncthreads();

    for (int idx = beg + t; idx < end; idx += 256) {
        const int2 s = stage[idx];
        const int local = (s.x >> sh) & 255;
        const unsigned vb = bf16_rnd(__int_as_float(s.y));
        unsigned packed;
        if (uside) packed = (unsigned)(s.x & 0xFFFF) | (vb << 16);
        else       packed = (unsigned)(s.x & 0x1FFFF) | ((vb & 0x7FFFu) << 17);
        const int slot = atomicAdd(&cur[local], 1);
        pairs[slot] = packed;
    }
}

// ---------------- SpMM: one 64-lane wave per destination row ----------------

template<bool USIDE>
__device__ __forceinline__ void decode_pair(unsigned s, int& c, float& v) {
    if (USIDE) { c = (int)(s & 0xFFFFu);  v = __uint_as_float(s & 0xFFFF0000u); }
    else       { c = (int)(s & 0x1FFFFu); v = __uint_as_float((s & 0xFFFE0000u) >> 1); }
}

// MODE 0: write bf16 dst only. MODE 1: out = (base + l1 + l2 + acc) * 0.25.
// start/end pinned to SGPR; pairs[] read at wave-uniform addresses (no shfl
// on the critical path); gathers issue 8-deep immediately.
template<int MODE, bool USIDE>
__device__ __forceinline__ void spmm_row_bf(
    const int* __restrict__ ptr, const unsigned* __restrict__ pairs,
    const unsigned* __restrict__ src, unsigned* __restrict__ dst,
    const unsigned* __restrict__ l1, const unsigned* __restrict__ l2,
    const float* __restrict__ base, float* __restrict__ out,
    int row, int lane)
{
    const int start = __builtin_amdgcn_readfirstlane(ptr[row]);
    const int end   = __builtin_amdgcn_readfirstlane(ptr[row + 1]);
    const unsigned* __restrict__ srcl = src + lane;   // gather = srcl[c * 64]
    v2f acc; acc.x = 0.f; acc.y = 0.f;

    int e = start;
    for (; e + 8 <= end; e += 8) {
        unsigned s[8]; int c[8]; float v[8]; unsigned g[8];
        #pragma unroll
        for (int k = 0; k < 8; ++k) s[k] = pairs[e + k];   // uniform addr
        #pragma unroll
        for (int k = 0; k < 8; ++k) {
            decode_pair<USIDE>(s[k], c[k], v[k]);
            g[k] = srcl[(size_t)c[k] * 64];
        }
        #pragma unroll
        for (int k = 0; k < 8; ++k) {
            v2f gv; gv.x = __uint_as_float(g[k] << 16);
            gv.y = __uint_as_float(g[k] & 0xFFFF0000u);
            acc += v[k] * gv;                               // v_pk_fma_f32
        }
    }
    for (; e < end; ++e) {
        const unsigned s = pairs[e];
        int c; float v;
        decode_pair<USIDE>(s, c, v);
        const unsigned g = srcl[(size_t)c * 64];
        v2f gv; gv.x = __uint_as_float(g << 16);
        gv.y = __uint_as_float(g & 0xFFFF0000u);
        acc += v * gv;
    }

    if (MODE == 0) {
        dst[(size_t)row * 64 + lane] = pack_bf16(acc.x, acc.y);
    } else {
        const unsigned a1 = l1[(size_t)row * 64 + lane];
        const unsigned a2 = l2[(size_t)row * 64 + lane];
        const size_t o = (size_t)row * EMBED_DIM + (lane << 1);
        const float2 bs = *reinterpret_cast<const float2*>(base + o);
        float2 r;
        r.x = (bs.x + __uint_as_float(a1 << 16) + __uint_as_float(a2 << 16) + acc.x) * 0.25f;
        r.y = (bs.y + __uint_as_float(a1 & 0xFFFF0000u) + __uint_as_float(a2 & 0xFFFF0000u) + acc.y) * 0.25f;
        *reinterpret_cast<float2*>(out + o) = r;
    }
}

template<int MODE>
__global__ __launch_bounds__(256) void csr_spmm_dual_bf(
    const int* __restrict__ ptr_u, const unsigned* __restrict__ pairs_u,
    const unsigned* __restrict__ src_u, unsigned* __restrict__ dst_u,
    const unsigned* __restrict__ l1_u, const unsigned* __restrict__ l2_u,
    const float* __restrict__ base_u, float* __restrict__ out_u,
    const int* __restrict__ ptr_i, const unsigned* __restrict__ pairs_i,
    const unsigned* __restrict__ src_i, unsigned* __restrict__ dst_i,
    const unsigned* __restrict__ l1_i, const unsigned* __restrict__ l2_i,
    const float* __restrict__ base_i, float* __restrict__ out_i,
    int GU)
{
    const int lane = threadIdx.x & 63;
    const int w = threadIdx.x >> 6;
    if ((int)blockIdx.x < GU) {
        const int row = blockIdx.x * 4 + w;
        if (row < NUM_USERS)
            spmm_row_bf<MODE, true>(ptr_u, pairs_u, src_u, dst_u, l1_u, l2_u, base_u, out_u, row, lane);
    } else {
        const int row = ((int)blockIdx.x - GU) * 4 + w;
        if (row < NUM_ITEMS)
            spmm_row_bf<MODE, false>(ptr_i, pairs_i, src_i, dst_i, l1_i, l2_i, base_i, out_i, row, lane);
    }
}

// ---------------- fallback (round-1 atomic path) ----------------

__global__ __launch_bounds__(256) void edge_spmm(
    const float* __restrict__ vals, const int* __restrict__ rows,
    const int* __restrict__ cols, const float* __restrict__ u_src,
    const float* __restrict__ i_src, float* __restrict__ u_dst,
    float* __restrict__ i_dst, int nnz)
{
    const int lane = threadIdx.x & 31;
    const int e = blockIdx.x * 8 + (threadIdx.x >> 5);
    if (e >= nnz) return;
    const float v = vals[e];
    const size_t ro = (size_t)rows[e] * EMBED_DIM + lane * 4;
    const size_t co = (size_t)cols[e] * EMBED_DIM + lane * 4;
    const float4 iv = *reinterpret_cast<const float4*>(i_src + co);
    const float4 uv = *reinterpret_cast<const float4*>(u_src + ro);
    atomicAdd(u_dst + ro + 0, v * iv.x); atomicAdd(u_dst + ro + 1, v * iv.y);
    atomicAdd(u_dst + ro + 2, v * iv.z); atomicAdd(u_dst + ro + 3, v * iv.w);
    atomicAdd(i_dst + co + 0, v * uv.x); atomicAdd(i_dst + co + 1, v * uv.y);
    atomicAdd(i_dst + co + 2, v * uv.z); atomicAdd(i_dst + co + 3, v * uv.w);
}

__global__ __launch_bounds__(256) void acc_scale(
    float* __restrict__ out, const float* __restrict__ x, long n, float scale)
{
    long i = ((long)blockIdx.x * blockDim.x + threadIdx.x) * 4;
    if (i >= n) return;
    float4 o = *reinterpret_cast<float4*>(out + i);
    float4 a = *reinterpret_cast<const float4*>(x + i);
    o.x = (o.x + a.x) * scale; o.y = (o.y + a.y) * scale;
    o.z = (o.z + a.z) * scale; o.w = (o.w + a.w) * scale;
    *reinterpret_cast<float4*>(out + i) = o;
}

// ---------------- launch ----------------

extern "C" void kernel_launch(void* const* d_in, const int* in_sizes, int n_in,
                              void* d_out, int out_size, void* d_ws, size_t ws_size,
                              hipStream_t stream)
{
    const float* user = (const float*)d_in[0];
    const float* item = (const float*)d_in[1];
    const float* vals = (const float*)d_in[2];
    const int*   rows = (const int*)d_in[3];
    const int*   cols = (const int*)d_in[4];

    const size_t UD = (size_t)NUM_USERS * EMBED_DIM;   // 12.8M
    const size_t ID = (size_t)NUM_ITEMS * EMBED_DIM;   //  6.4M

    float* out_u = (float*)d_out;
    float* out_i = out_u + UD;

    // ---- CSR-path workspace layout ----
    char* ws = (char*)d_ws;
    unsigned* user_bf = (unsigned*)ws;              ws += UD * 2;
    unsigned* item_bf = (unsigned*)ws;              ws += ID * 2;
    unsigned* uA = (unsigned*)ws;                   ws += UD * 2;
    unsigned* uB = (unsigned*)ws;                   ws += UD * 2;
    unsigned* iA = (unsigned*)ws;                   ws += ID * 2;
    unsigned* iB = (unsigned*)ws;                   ws += ID * 2;
    unsigned* pairs_u = (unsigned*)ws;              ws += (size_t)NNZ_COUNT * 4;
    unsigned* pairs_i = (unsigned*)ws;              ws += (size_t)NNZ_COUNT * 4;
    int2* stage_u = (int2*)ws;                      ws += (size_t)NNZ_COUNT * 8;
    int2* stage_i = (int2*)ws;                      ws += (size_t)NNZ_COUNT * 8;
    int* ptr_u = (int*)ws;                          ws += (NUM_USERS + 1) * 4;
    int* ptr_i = (int*)ws;                          ws += (NUM_ITEMS + 1) * 4;
    int* bbase_u = (int*)ws;                        ws += (NBUCK_U + 1) * 4;
    int* bbase_i = (int*)ws;                        ws += (NBUCK_I + 1) * 4;
    const size_t REQ = (size_t)(ws - (char*)d_ws);  // ~164 MB

    // hist/offs/tot (~1.16 MB) alias into pairs_u: all consumed by
    // msplit_offsets/scan_buckets/msplit_scatter before bucket_build ever
    // writes pairs_u (disjoint lifetimes). bbase is NOT aliased.
    int* hist_u = (int*)pairs_u;
    int* hist_i = hist_u + NBUCK_U * NBLK;
    int* offs_u = hist_i + NBUCK_I * NBLK;
    int* offs_i = offs_u + NBLK * NBUCK_U;
    int* tot_u  = offs_i + NBLK * NBUCK_I;
    int* tot_i  = tot_u + NBUCK_U;

    if (ws_size >= REQ) {
        // ---- prep: bf16 copies of the input tables ----
        const int NA8 = (int)(UD / 8), NB8 = (int)(ID / 8);
        to_bf16_dual<<<(NA8 + NB8 + 255) / 256, 256, 0, stream>>>(
            user, user_bf, NA8, item, item_bf, NB8);

        // ---- atomic-free CSR build ----
        msplit_hist<<<NBLK, 256, 0, stream>>>(rows, cols, hist_u, hist_i);
        msplit_offsets<<<NBUCK_U + NBUCK_I, 256, 0, stream>>>(
            hist_u, hist_i, offs_u, offs_i, tot_u, tot_i);
        scan_buckets<<<2, 512, 0, stream>>>(tot_u, bbase_u, tot_i, bbase_i);
        msplit_scatter<<<NBLK, 256, 0, stream>>>(
            rows, cols, vals, offs_u, offs_i, bbase_u, bbase_i, stage_u, stage_i);
        bucket_build<<<NBUCK_U + NBUCK_I, 256, 0, stream>>>(
            bbase_u, stage_u, pairs_u, ptr_u,
            bbase_i, stage_i, pairs_i, ptr_i);

        const int GU = (NUM_USERS + 3) / 4;   // 25000
        const int GI = (NUM_ITEMS + 3) / 4;   // 12500

        // layer 1: src = bf16 inputs -> uA/iA (dst only, no sum traffic)
        csr_spmm_dual_bf<0><<<GU + GI, 256, 0, stream>>>(
            ptr_u, pairs_u, item_bf, uA, nullptr, nullptr, nullptr, nullptr,
            ptr_i, pairs_i, user_bf, iA, nullptr, nullptr, nullptr, nullptr, GU);
        // layer 2: src = uA/iA -> uB/iB
        csr_spmm_dual_bf<0><<<GU + GI, 256, 0, stream>>>(
            ptr_u, pairs_u, iA, uB, nullptr, nullptr, nullptr, nullptr,
            ptr_i, pairs_i, uA, iB, nullptr, nullptr, nullptr, nullptr, GU);
        // layer 3: fused epilogue out = (base + l1 + l2 + acc) / 4
        csr_spmm_dual_bf<1><<<GU + GI, 256, 0, stream>>>(
            ptr_u, pairs_u, iB, nullptr, uA, uB, user, out_u,
            ptr_i, pairs_i, uB, nullptr, iA, iB, item, out_i, GU);
    } else {
        // ---- fallback: round-1 atomic path (fp32 buffers carved from ws) ----
        char* fw = (char*)d_ws;
        float* fuA = (float*)fw;                    fw += UD * 4;
        float* fuB = (float*)fw;                    fw += UD * 4;
        float* fiA = (float*)fw;                    fw += ID * 4;
        float* fiB = (float*)fw;                    fw += ID * 4;

        const int EDGE_BLOCKS = (NNZ_COUNT + 7) / 8;
        const int ACC_U = (int)(UD / 1024), ACC_I = (int)(ID / 1024);

        hipMemcpyAsync(out_u, user, UD * 4, hipMemcpyDeviceToDevice, stream);
        hipMemcpyAsync(out_i, item, ID * 4, hipMemcpyDeviceToDevice, stream);

        hipMemsetAsync(fuA, 0, UD * 4, stream);
        hipMemsetAsync(fiA, 0, ID * 4, stream);
        edge_spmm<<<EDGE_BLOCKS, 256, 0, stream>>>(vals, rows, cols, user, item, fuA, fiA, NNZ_COUNT);
        acc_scale<<<ACC_U, 256, 0, stream>>>(out_u, fuA, (long)UD, 1.0f);
        acc_scale<<<ACC_I, 256, 0, stream>>>(out_i, fiA, (long)ID, 1.0f);

        hipMemsetAsync(fuB, 0, UD * 4, stream);
        hipMemsetAsync(fiB, 0, ID * 4, stream);
        edge_spmm<<<EDGE_BLOCKS, 256, 0, stream>>>(vals, rows, cols, fuA, fiA, fuB, fiB, NNZ_COUNT);
        acc_scale<<<ACC_U, 256, 0, stream>>>(out_u, fuB, (long)UD, 1.0f);
        acc_scale<<<ACC_I, 256, 0, stream>>>(out_i, fiB, (long)ID, 1.0f);

        hipMemsetAsync(fuA, 0, UD * 4, stream);
        hipMemsetAsync(fiA, 0, ID * 4, stream);
        edge_spmm<<<EDGE_BLOCKS, 256, 0, stream>>>(vals, rows, cols, fuB, fiB, fuA, fiA, NNZ_COUNT);
        acc_scale<<<ACC_U, 256, 0, stream>>>(out_u, fuA, (long)UD, 0.25f);
        acc_scale<<<ACC_I, 256, 0, stream>>>(out_i, fiA, (long)ID, 0.25f);
    }
}

// Round 6
// 639.705 us; speedup vs baseline: 1.1070x; 1.0193x over previous
//
#include <hip/hip_runtime.h>

// LightGCN-style 3-layer bipartite propagation.
// R11 = R10 with the compile fix: __builtin_nontemporal_* requires scalar or
// ext-vector types, not HIP_vector_type float2 -> use v2f for the 8B epilogue
// load/store. Theory unchanged from R10:
// R9 halved VALUBusy (47->22%) with ZERO dur change -> SpMM is memory-
// system-bound at ~3.9 TB/s on a 593MB mix (500MB random 256B gathers).
// Last non-roofline hypothesis: latency/pollution residue. Two cheap fixes:
//  (a) 16-deep gather batches (was 8) — doubles per-wave MLP.
//  (b) nontemporal loads/stores on ALL streams (dst, l1, l2, base, out) so
//      write/read-once traffic stops evicting gather-hot table lines from
//      the 4MB per-XCD L2.
// If SpMM dur and FETCH are unchanged, the 256B-random HBM service rate is
// the roofline (~148us/dispatch floor).

#define NUM_USERS 100000
#define NUM_ITEMS 50000
#define EMBED_DIM 128
#define NNZ_COUNT 2000000
#define NBUCK_U 391            // ceil(100000/256)
#define NBUCK_I 196            // ceil(50000/256)
#define EPB 8192               // edges per multisplit block
#define NBLK 245               // ceil(NNZ_COUNT/EPB)

typedef float v2f __attribute__((ext_vector_type(2)));

// ---------------- bf16 helpers (manual RTNE) ----------------

__device__ __forceinline__ unsigned bf16_rnd(float f) {
    unsigned u = __float_as_uint(f);
    return (u + 0x7FFFu + ((u >> 16) & 1u)) >> 16;
}
__device__ __forceinline__ unsigned pack_bf16(float x, float y) {
    return bf16_rnd(x) | (bf16_rnd(y) << 16);
}

// Both embedding tables in one launch.
__global__ __launch_bounds__(256) void to_bf16_dual(
    const float* __restrict__ a, unsigned* __restrict__ oa, int na8,
    const float* __restrict__ b, unsigned* __restrict__ ob, int nb8)
{
    int i = blockIdx.x * 256 + threadIdx.x;
    const float4* s4; uint4* d4;
    if (i < na8) {
        s4 = reinterpret_cast<const float4*>(a) + i * 2;
        d4 = reinterpret_cast<uint4*>(oa) + i;
    } else {
        i -= na8;
        if (i >= nb8) return;
        s4 = reinterpret_cast<const float4*>(b) + i * 2;
        d4 = reinterpret_cast<uint4*>(ob) + i;
    }
    float4 x = s4[0], y = s4[1];
    uint4 r;
    r.x = pack_bf16(x.x, x.y); r.y = pack_bf16(x.z, x.w);
    r.z = pack_bf16(y.x, y.y); r.w = pack_bf16(y.z, y.w);
    *d4 = r;
}

// ---------------- LDS-aggregated multisplit (phase A) ----------------

__global__ __launch_bounds__(256) void msplit_hist(
    const int* __restrict__ rows, const int* __restrict__ cols,
    int* __restrict__ hist_u, int* __restrict__ hist_i)
{
    __shared__ int h[NBUCK_U + NBUCK_I];
    for (int i = threadIdx.x; i < NBUCK_U + NBUCK_I; i += 256) h[i] = 0;
    __syncthreads();
    const int base = blockIdx.x * EPB;
    const int end = min(base + EPB, NNZ_COUNT);
    for (int e = base + threadIdx.x; e < end; e += 256) {
        atomicAdd(&h[rows[e] >> 8], 1);
        atomicAdd(&h[NBUCK_U + (cols[e] >> 8)], 1);
    }
    __syncthreads();
    for (int b = threadIdx.x; b < NBUCK_U; b += 256)
        hist_u[b * NBLK + blockIdx.x] = h[b];
    for (int b = threadIdx.x; b < NBUCK_I; b += 256)
        hist_i[b * NBLK + blockIdx.x] = h[NBUCK_U + b];
}

// One block per bucket: exclusive scan over its NBLK counts (bucket-relative)
// + emit the bucket total for the cross-bucket scan.
__global__ __launch_bounds__(256) void msplit_offsets(
    const int* __restrict__ hist_u, const int* __restrict__ hist_i,
    int* __restrict__ offs_u, int* __restrict__ offs_i,
    int* __restrict__ tot_u, int* __restrict__ tot_i)
{
    __shared__ int buf[256];
    int b = blockIdx.x;
    const int* hist; int* offs; int* tot; int nbuck;
    if (b < NBUCK_U) { hist = hist_u; offs = offs_u; tot = tot_u; nbuck = NBUCK_U; }
    else { b -= NBUCK_U; hist = hist_i; offs = offs_i; tot = tot_i; nbuck = NBUCK_I; }
    const int t = threadIdx.x;
    const int x = (t < NBLK) ? hist[b * NBLK + t] : 0;
    buf[t] = x;
    __syncthreads();
    for (int d = 1; d < 256; d <<= 1) {
        const int y = (t >= d) ? buf[t - d] : 0;
        __syncthreads();
        buf[t] += y;
        __syncthreads();
    }
    if (t < NBLK) offs[t * nbuck + b] = buf[t] - x;   // bucket-relative
    if (t == 255) tot[b] = buf[255];                  // bucket total
}

// Cross-bucket exclusive scan (block 0 = users, 1 = items).
__global__ __launch_bounds__(512) void scan_buckets(
    const int* __restrict__ tot_u, int* __restrict__ bbase_u,
    const int* __restrict__ tot_i, int* __restrict__ bbase_i)
{
    __shared__ int buf[512];
    const int t = threadIdx.x;
    const int* tot; int* bbase; int nb;
    if (blockIdx.x == 0) { tot = tot_u; bbase = bbase_u; nb = NBUCK_U; }
    else                 { tot = tot_i; bbase = bbase_i; nb = NBUCK_I; }
    const int v = (t < nb) ? tot[t] : 0;
    buf[t] = v;
    __syncthreads();
    for (int d = 1; d < 512; d <<= 1) {
        const int y = (t >= d) ? buf[t - d] : 0;
        __syncthreads();
        buf[t] += y;
        __syncthreads();
    }
    if (t <= nb) bbase[t] = buf[t] - v;   // exclusive; bbase[nb] = total
}

// Scatter with LDS cursors: writes land in bucket-contiguous runs.
// u stage: col(16b) | local_row(8b)<<16 ; i stage: row(17b) | local_col(8b)<<17.
__global__ __launch_bounds__(256) void msplit_scatter(
    const int* __restrict__ rows, const int* __restrict__ cols,
    const float* __restrict__ vals,
    const int* __restrict__ offs_u, const int* __restrict__ offs_i,
    const int* __restrict__ bbase_u, const int* __restrict__ bbase_i,
    int2* __restrict__ stage_u, int2* __restrict__ stage_i)
{
    __shared__ int cu[NBUCK_U];
    __shared__ int ci[NBUCK_I];
    const int t = threadIdx.x;
    for (int b = t; b < NBUCK_U; b += 256)
        cu[b] = offs_u[blockIdx.x * NBUCK_U + b] + bbase_u[b];
    for (int b = t; b < NBUCK_I; b += 256)
        ci[b] = offs_i[blockIdx.x * NBUCK_I + b] + bbase_i[b];
    __syncthreads();
    const int base = blockIdx.x * EPB;
    const int end = min(base + EPB, NNZ_COUNT);
    for (int e = base + t; e < end; e += 256) {
        const int r = rows[e];
        const int c = cols[e];
        const int vb = __float_as_int(vals[e]);
        const int su = atomicAdd(&cu[r >> 8], 1);
        stage_u[su] = make_int2(c | ((r & 255) << 16), vb);
        const int si = atomicAdd(&ci[c >> 8], 1);
        stage_i[si] = make_int2(r | ((c & 255) << 17), vb);
    }
}

// Phase B: one block per bucket. LDS histogram of the bucket's 256 local
// rows -> LDS scan -> per-row CSR pointers written inline -> LDS-cursor
// scatter into packed 4B pairs:
//   u pair: col(16b) | bf16(val)<<16
//   i pair: row(17b) | (bf16(val)&0x7FFF)<<17   (val >= 0, sign dropped)
__global__ __launch_bounds__(256) void bucket_build(
    const int* __restrict__ bbase_u, const int2* __restrict__ stage_u,
    unsigned* __restrict__ pairs_u, int* __restrict__ ptr_u,
    const int* __restrict__ bbase_i, const int2* __restrict__ stage_i,
    unsigned* __restrict__ pairs_i, int* __restrict__ ptr_i)
{
    __shared__ int hcnt[256];
    __shared__ int buf[256];
    __shared__ int cur[256];
    const int t = threadIdx.x;
    int b = blockIdx.x;
    const bool uside = (b < NBUCK_U);
    const int* bbase; const int2* stage; unsigned* pairs; int* ptr; int n; int sh;
    if (uside) { bbase = bbase_u; stage = stage_u; pairs = pairs_u; ptr = ptr_u; n = NUM_USERS; sh = 16; }
    else { b -= NBUCK_U; bbase = bbase_i; stage = stage_i; pairs = pairs_i; ptr = ptr_i; n = NUM_ITEMS; sh = 17; }
    const int beg = bbase[b];
    const int end = bbase[b + 1];

    hcnt[t] = 0;
    __syncthreads();
    for (int idx = beg + t; idx < end; idx += 256)
        atomicAdd(&hcnt[(stage[idx].x >> sh) & 255], 1);
    __syncthreads();

    const int v = hcnt[t];
    buf[t] = v;
    __syncthreads();
    for (int d = 1; d < 256; d <<= 1) {
        const int y = (t >= d) ? buf[t - d] : 0;
        __syncthreads();
        buf[t] += y;
        __syncthreads();
    }
    const int rowbase = beg + buf[t] - v;   // exclusive scan + bucket base
    cur[t] = rowbase;
    const int first = b << 8;
    if (first + t < n) ptr[first + t] = rowbase;
    if (first + t == n) ptr[n] = end;                       // partial last bucket
    else if (first + 256 == n && t == 0) ptr[n] = end;      // exact-fit last bucket
    __syncthreads();

    for (int idx = beg + t; idx < end; idx += 256) {
        const int2 s = stage[idx];
        const int local = (s.x >> sh) & 255;
        const unsigned vb = bf16_rnd(__int_as_float(s.y));
        unsigned packed;
        if (uside) packed = (unsigned)(s.x & 0xFFFF) | (vb << 16);
        else       packed = (unsigned)(s.x & 0x1FFFF) | ((vb & 0x7FFFu) << 17);
        const int slot = atomicAdd(&cur[local], 1);
        pairs[slot] = packed;
    }
}

// ---------------- SpMM: one 64-lane wave per destination row ----------------

template<bool USIDE>
__device__ __forceinline__ void decode_pair(unsigned s, int& c, float& v) {
    if (USIDE) { c = (int)(s & 0xFFFFu);  v = __uint_as_float(s & 0xFFFF0000u); }
    else       { c = (int)(s & 0x1FFFFu); v = __uint_as_float((s & 0xFFFE0000u) >> 1); }
}

// MODE 0: write bf16 dst only. MODE 1: out = (base + l1 + l2 + acc) * 0.25.
// start/end pinned to SGPR; pairs[] read at wave-uniform addresses; 16-deep
// gather batches; all streaming accesses nontemporal (protect L2 for gathers).
template<int MODE, bool USIDE>
__device__ __forceinline__ void spmm_row_bf(
    const int* __restrict__ ptr, const unsigned* __restrict__ pairs,
    const unsigned* __restrict__ src, unsigned* __restrict__ dst,
    const unsigned* __restrict__ l1, const unsigned* __restrict__ l2,
    const float* __restrict__ base, float* __restrict__ out,
    int row, int lane)
{
    const int start = __builtin_amdgcn_readfirstlane(ptr[row]);
    const int end   = __builtin_amdgcn_readfirstlane(ptr[row + 1]);
    const unsigned* __restrict__ srcl = src + lane;   // gather = srcl[c * 64]
    v2f acc; acc.x = 0.f; acc.y = 0.f;

    int e = start;
    for (; e + 16 <= end; e += 16) {
        unsigned s[16]; int c[16]; float v[16]; unsigned g[16];
        #pragma unroll
        for (int k = 0; k < 16; ++k) s[k] = pairs[e + k];   // uniform addr
        #pragma unroll
        for (int k = 0; k < 16; ++k) {
            decode_pair<USIDE>(s[k], c[k], v[k]);
            g[k] = srcl[(size_t)c[k] * 64];
        }
        #pragma unroll
        for (int k = 0; k < 16; ++k) {
            v2f gv; gv.x = __uint_as_float(g[k] << 16);
            gv.y = __uint_as_float(g[k] & 0xFFFF0000u);
            acc += v[k] * gv;                               // v_pk_fma_f32
        }
    }
    for (; e + 8 <= end; e += 8) {
        unsigned s[8]; int c[8]; float v[8]; unsigned g[8];
        #pragma unroll
        for (int k = 0; k < 8; ++k) s[k] = pairs[e + k];
        #pragma unroll
        for (int k = 0; k < 8; ++k) {
            decode_pair<USIDE>(s[k], c[k], v[k]);
            g[k] = srcl[(size_t)c[k] * 64];
        }
        #pragma unroll
        for (int k = 0; k < 8; ++k) {
            v2f gv; gv.x = __uint_as_float(g[k] << 16);
            gv.y = __uint_as_float(g[k] & 0xFFFF0000u);
            acc += v[k] * gv;
        }
    }
    for (; e < end; ++e) {
        const unsigned s = pairs[e];
        int c; float v;
        decode_pair<USIDE>(s, c, v);
        const unsigned g = srcl[(size_t)c * 64];
        v2f gv; gv.x = __uint_as_float(g << 16);
        gv.y = __uint_as_float(g & 0xFFFF0000u);
        acc += v * gv;
    }

    if (MODE == 0) {
        __builtin_nontemporal_store(pack_bf16(acc.x, acc.y),
                                    dst + (size_t)row * 64 + lane);
    } else {
        const unsigned a1 = __builtin_nontemporal_load(l1 + (size_t)row * 64 + lane);
        const unsigned a2 = __builtin_nontemporal_load(l2 + (size_t)row * 64 + lane);
        const size_t o = (size_t)row * EMBED_DIM + (lane << 1);
        const v2f bs = __builtin_nontemporal_load(
            reinterpret_cast<const v2f*>(base + o));
        v2f r;
        r.x = (bs.x + __uint_as_float(a1 << 16) + __uint_as_float(a2 << 16) + acc.x) * 0.25f;
        r.y = (bs.y + __uint_as_float(a1 & 0xFFFF0000u) + __uint_as_float(a2 & 0xFFFF0000u) + acc.y) * 0.25f;
        __builtin_nontemporal_store(r, reinterpret_cast<v2f*>(out + o));
    }
}

template<int MODE>
__global__ __launch_bounds__(256) void csr_spmm_dual_bf(
    const int* __restrict__ ptr_u, const unsigned* __restrict__ pairs_u,
    const unsigned* __restrict__ src_u, unsigned* __restrict__ dst_u,
    const unsigned* __restrict__ l1_u, const unsigned* __restrict__ l2_u,
    const float* __restrict__ base_u, float* __restrict__ out_u,
    const int* __restrict__ ptr_i, const unsigned* __restrict__ pairs_i,
    const unsigned* __restrict__ src_i, unsigned* __restrict__ dst_i,
    const unsigned* __restrict__ l1_i, const unsigned* __restrict__ l2_i,
    const float* __restrict__ base_i, float* __restrict__ out_i,
    int GU)
{
    const int lane = threadIdx.x & 63;
    const int w = threadIdx.x >> 6;
    if ((int)blockIdx.x < GU) {
        const int row = blockIdx.x * 4 + w;
        if (row < NUM_USERS)
            spmm_row_bf<MODE, true>(ptr_u, pairs_u, src_u, dst_u, l1_u, l2_u, base_u, out_u, row, lane);
    } else {
        const int row = ((int)blockIdx.x - GU) * 4 + w;
        if (row < NUM_ITEMS)
            spmm_row_bf<MODE, false>(ptr_i, pairs_i, src_i, dst_i, l1_i, l2_i, base_i, out_i, row, lane);
    }
}

// ---------------- fallback (round-1 atomic path) ----------------

__global__ __launch_bounds__(256) void edge_spmm(
    const float* __restrict__ vals, const int* __restrict__ rows,
    const int* __restrict__ cols, const float* __restrict__ u_src,
    const float* __restrict__ i_src, float* __restrict__ u_dst,
    float* __restrict__ i_dst, int nnz)
{
    const int lane = threadIdx.x & 31;
    const int e = blockIdx.x * 8 + (threadIdx.x >> 5);
    if (e >= nnz) return;
    const float v = vals[e];
    const size_t ro = (size_t)rows[e] * EMBED_DIM + lane * 4;
    const size_t co = (size_t)cols[e] * EMBED_DIM + lane * 4;
    const float4 iv = *reinterpret_cast<const float4*>(i_src + co);
    const float4 uv = *reinterpret_cast<const float4*>(u_src + ro);
    atomicAdd(u_dst + ro + 0, v * iv.x); atomicAdd(u_dst + ro + 1, v * iv.y);
    atomicAdd(u_dst + ro + 2, v * iv.z); atomicAdd(u_dst + ro + 3, v * iv.w);
    atomicAdd(i_dst + co + 0, v * uv.x); atomicAdd(i_dst + co + 1, v * uv.y);
    atomicAdd(i_dst + co + 2, v * uv.z); atomicAdd(i_dst + co + 3, v * uv.w);
}

__global__ __launch_bounds__(256) void acc_scale(
    float* __restrict__ out, const float* __restrict__ x, long n, float scale)
{
    long i = ((long)blockIdx.x * blockDim.x + threadIdx.x) * 4;
    if (i >= n) return;
    float4 o = *reinterpret_cast<float4*>(out + i);
    float4 a = *reinterpret_cast<const float4*>(x + i);
    o.x = (o.x + a.x) * scale; o.y = (o.y + a.y) * scale;
    o.z = (o.z + a.z) * scale; o.w = (o.w + a.w) * scale;
    *reinterpret_cast<float4*>(out + i) = o;
}

// ---------------- launch ----------------

extern "C" void kernel_launch(void* const* d_in, const int* in_sizes, int n_in,
                              void* d_out, int out_size, void* d_ws, size_t ws_size,
                              hipStream_t stream)
{
    const float* user = (const float*)d_in[0];
    const float* item = (const float*)d_in[1];
    const float* vals = (const float*)d_in[2];
    const int*   rows = (const int*)d_in[3];
    const int*   cols = (const int*)d_in[4];

    const size_t UD = (size_t)NUM_USERS * EMBED_DIM;   // 12.8M
    const size_t ID = (size_t)NUM_ITEMS * EMBED_DIM;   //  6.4M

    float* out_u = (float*)d_out;
    float* out_i = out_u + UD;

    // ---- CSR-path workspace layout ----
    char* ws = (char*)d_ws;
    unsigned* user_bf = (unsigned*)ws;              ws += UD * 2;
    unsigned* item_bf = (unsigned*)ws;              ws += ID * 2;
    unsigned* uA = (unsigned*)ws;                   ws += UD * 2;
    unsigned* uB = (unsigned*)ws;                   ws += UD * 2;
    unsigned* iA = (unsigned*)ws;                   ws += ID * 2;
    unsigned* iB = (unsigned*)ws;                   ws += ID * 2;
    unsigned* pairs_u = (unsigned*)ws;              ws += (size_t)NNZ_COUNT * 4;
    unsigned* pairs_i = (unsigned*)ws;              ws += (size_t)NNZ_COUNT * 4;
    int2* stage_u = (int2*)ws;                      ws += (size_t)NNZ_COUNT * 8;
    int2* stage_i = (int2*)ws;                      ws += (size_t)NNZ_COUNT * 8;
    int* ptr_u = (int*)ws;                          ws += (NUM_USERS + 1) * 4;
    int* ptr_i = (int*)ws;                          ws += (NUM_ITEMS + 1) * 4;
    int* bbase_u = (int*)ws;                        ws += (NBUCK_U + 1) * 4;
    int* bbase_i = (int*)ws;                        ws += (NBUCK_I + 1) * 4;
    const size_t REQ = (size_t)(ws - (char*)d_ws);  // ~164 MB

    // hist/offs/tot (~1.16 MB) alias into pairs_u: all consumed by
    // msplit_offsets/scan_buckets/msplit_scatter before bucket_build ever
    // writes pairs_u (disjoint lifetimes). bbase is NOT aliased.
    int* hist_u = (int*)pairs_u;
    int* hist_i = hist_u + NBUCK_U * NBLK;
    int* offs_u = hist_i + NBUCK_I * NBLK;
    int* offs_i = offs_u + NBLK * NBUCK_U;
    int* tot_u  = offs_i + NBLK * NBUCK_I;
    int* tot_i  = tot_u + NBUCK_U;

    if (ws_size >= REQ) {
        // ---- prep: bf16 copies of the input tables ----
        const int NA8 = (int)(UD / 8), NB8 = (int)(ID / 8);
        to_bf16_dual<<<(NA8 + NB8 + 255) / 256, 256, 0, stream>>>(
            user, user_bf, NA8, item, item_bf, NB8);

        // ---- atomic-free CSR build ----
        msplit_hist<<<NBLK, 256, 0, stream>>>(rows, cols, hist_u, hist_i);
        msplit_offsets<<<NBUCK_U + NBUCK_I, 256, 0, stream>>>(
            hist_u, hist_i, offs_u, offs_i, tot_u, tot_i);
        scan_buckets<<<2, 512, 0, stream>>>(tot_u, bbase_u, tot_i, bbase_i);
        msplit_scatter<<<NBLK, 256, 0, stream>>>(
            rows, cols, vals, offs_u, offs_i, bbase_u, bbase_i, stage_u, stage_i);
        bucket_build<<<NBUCK_U + NBUCK_I, 256, 0, stream>>>(
            bbase_u, stage_u, pairs_u, ptr_u,
            bbase_i, stage_i, pairs_i, ptr_i);

        const int GU = (NUM_USERS + 3) / 4;   // 25000
        const int GI = (NUM_ITEMS + 3) / 4;   // 12500

        // layer 1: src = bf16 inputs -> uA/iA (dst only, no sum traffic)
        csr_spmm_dual_bf<0><<<GU + GI, 256, 0, stream>>>(
            ptr_u, pairs_u, item_bf, uA, nullptr, nullptr, nullptr, nullptr,
            ptr_i, pairs_i, user_bf, iA, nullptr, nullptr, nullptr, nullptr, GU);
        // layer 2: src = uA/iA -> uB/iB
        csr_spmm_dual_bf<0><<<GU + GI, 256, 0, stream>>>(
            ptr_u, pairs_u, iA, uB, nullptr, nullptr, nullptr, nullptr,
            ptr_i, pairs_i, uA, iB, nullptr, nullptr, nullptr, nullptr, GU);
        // layer 3: fused epilogue out = (base + l1 + l2 + acc) / 4
        csr_spmm_dual_bf<1><<<GU + GI, 256, 0, stream>>>(
            ptr_u, pairs_u, iB, nullptr, uA, uB, user, out_u,
            ptr_i, pairs_i, uB, nullptr, iA, iB, item, out_i, GU);
    } else {
        // ---- fallback: round-1 atomic path (fp32 buffers carved from ws) ----
        char* fw = (char*)d_ws;
        float* fuA = (float*)fw;                    fw += UD * 4;
        float* fuB = (float*)fw;                    fw += UD * 4;
        float* fiA = (float*)fw;                    fw += ID * 4;
        float* fiB = (float*)fw;                    fw += ID * 4;

        const int EDGE_BLOCKS = (NNZ_COUNT + 7) / 8;
        const int ACC_U = (int)(UD / 1024), ACC_I = (int)(ID / 1024);

        hipMemcpyAsync(out_u, user, UD * 4, hipMemcpyDeviceToDevice, stream);
        hipMemcpyAsync(out_i, item, ID * 4, hipMemcpyDeviceToDevice, stream);

        hipMemsetAsync(fuA, 0, UD * 4, stream);
        hipMemsetAsync(fiA, 0, ID * 4, stream);
        edge_spmm<<<EDGE_BLOCKS, 256, 0, stream>>>(vals, rows, cols, user, item, fuA, fiA, NNZ_COUNT);
        acc_scale<<<ACC_U, 256, 0, stream>>>(out_u, fuA, (long)UD, 1.0f);
        acc_scale<<<ACC_I, 256, 0, stream>>>(out_i, fiA, (long)ID, 1.0f);

        hipMemsetAsync(fuB, 0, UD * 4, stream);
        hipMemsetAsync(fiB, 0, ID * 4, stream);
        edge_spmm<<<EDGE_BLOCKS, 256, 0, stream>>>(vals, rows, cols, fuA, fiA, fuB, fiB, NNZ_COUNT);
        acc_scale<<<ACC_U, 256, 0, stream>>>(out_u, fuB, (long)UD, 1.0f);
        acc_scale<<<ACC_I, 256, 0, stream>>>(out_i, fiB, (long)ID, 1.0f);

        hipMemsetAsync(fuA, 0, UD * 4, stream);
        hipMemsetAsync(fiA, 0, ID * 4, stream);
        edge_spmm<<<EDGE_BLOCKS, 256, 0, stream>>>(vals, rows, cols, fuB, fiB, fuA, fiA, NNZ_COUNT);
        acc_scale<<<ACC_U, 256, 0, stream>>>(out_u, fuA, (long)UD, 0.25f);
        acc_scale<<<ACC_I, 256, 0, stream>>>(out_i, fiA, (long)ID, 0.25f);
    }
}

// Round 7
// 600.558 us; speedup vs baseline: 1.1792x; 1.0652x over previous
//
#include <hip/hip_runtime.h>

// LightGCN-style 3-layer bipartite propagation.
// R12: SpMM is at its memory-service rate (five variants all ~146-153us,
// ~4 TB/s L2-miss service, VALUBusy 22%) — leave it. Remaining fat is the
// BUILD: msplit_scatter wrote 32MB as isolated 8B random writes and
// bucket_build wrote 16MB as isolated 4B writes -> 64B-line write
// amplification (4-8x hidden traffic). Fix: LDS-staged multisplit — sort
// each block's edges in LDS (local hist + scan + cursors), then dump bucket
// runs CONTIGUOUSLY (consecutive threads -> consecutive addresses).
//  - msplit_scatter: 512 threads, EPB 4096, U-phase then I-phase reusing
//    46KB LDS (ed0/ed1/bpos + scan arrays), 3 blocks/CU.
//  - bucket_build: stage the bucket's packed pairs in 48KB LDS (cap 12288
//    entries; avg u=5.1k, i=10.2k; direct-scatter fallback if over cap),
//    then coalesced dump + same inline ptr[] build.
// R11's SpMM (SGPR pair loads, 16-deep gathers, nontemporal streams,
// deferred sum, packed 4B pairs) kept unchanged.

#define NUM_USERS 100000
#define NUM_ITEMS 50000
#define EMBED_DIM 128
#define NNZ_COUNT 2000000
#define NBUCK_U 391            // ceil(100000/256)
#define NBUCK_I 196            // ceil(50000/256)
#define EPB 4096               // edges per multisplit block
#define NBLK 489               // ceil(NNZ_COUNT/EPB)
#define BCAP 12288             // bucket_build LDS staging cap (entries)

typedef float v2f __attribute__((ext_vector_type(2)));

// ---------------- bf16 helpers (manual RTNE) ----------------

__device__ __forceinline__ unsigned bf16_rnd(float f) {
    unsigned u = __float_as_uint(f);
    return (u + 0x7FFFu + ((u >> 16) & 1u)) >> 16;
}
__device__ __forceinline__ unsigned pack_bf16(float x, float y) {
    return bf16_rnd(x) | (bf16_rnd(y) << 16);
}

// Both embedding tables in one launch.
__global__ __launch_bounds__(256) void to_bf16_dual(
    const float* __restrict__ a, unsigned* __restrict__ oa, int na8,
    const float* __restrict__ b, unsigned* __restrict__ ob, int nb8)
{
    int i = blockIdx.x * 256 + threadIdx.x;
    const float4* s4; uint4* d4;
    if (i < na8) {
        s4 = reinterpret_cast<const float4*>(a) + i * 2;
        d4 = reinterpret_cast<uint4*>(oa) + i;
    } else {
        i -= na8;
        if (i >= nb8) return;
        s4 = reinterpret_cast<const float4*>(b) + i * 2;
        d4 = reinterpret_cast<uint4*>(ob) + i;
    }
    float4 x = s4[0], y = s4[1];
    uint4 r;
    r.x = pack_bf16(x.x, x.y); r.y = pack_bf16(x.z, x.w);
    r.z = pack_bf16(y.x, y.y); r.w = pack_bf16(y.z, y.w);
    *d4 = r;
}

// ---------------- LDS-aggregated multisplit (phase A) ----------------

__global__ __launch_bounds__(256) void msplit_hist(
    const int* __restrict__ rows, const int* __restrict__ cols,
    int* __restrict__ hist_u, int* __restrict__ hist_i)
{
    __shared__ int h[NBUCK_U + NBUCK_I];
    for (int i = threadIdx.x; i < NBUCK_U + NBUCK_I; i += 256) h[i] = 0;
    __syncthreads();
    const int base = blockIdx.x * EPB;
    const int end = min(base + EPB, NNZ_COUNT);
    for (int e = base + threadIdx.x; e < end; e += 256) {
        atomicAdd(&h[rows[e] >> 8], 1);
        atomicAdd(&h[NBUCK_U + (cols[e] >> 8)], 1);
    }
    __syncthreads();
    for (int b = threadIdx.x; b < NBUCK_U; b += 256)
        hist_u[b * NBLK + blockIdx.x] = h[b];
    for (int b = threadIdx.x; b < NBUCK_I; b += 256)
        hist_i[b * NBLK + blockIdx.x] = h[NBUCK_U + b];
}

// One block per bucket: exclusive scan over its NBLK (=489) counts
// (bucket-relative) + emit the bucket total. 512-thread scan.
__global__ __launch_bounds__(512) void msplit_offsets(
    const int* __restrict__ hist_u, const int* __restrict__ hist_i,
    int* __restrict__ offs_u, int* __restrict__ offs_i,
    int* __restrict__ tot_u, int* __restrict__ tot_i)
{
    __shared__ int buf[512];
    int b = blockIdx.x;
    const int* hist; int* offs; int* tot; int nbuck;
    if (b < NBUCK_U) { hist = hist_u; offs = offs_u; tot = tot_u; nbuck = NBUCK_U; }
    else { b -= NBUCK_U; hist = hist_i; offs = offs_i; tot = tot_i; nbuck = NBUCK_I; }
    const int t = threadIdx.x;
    const int x = (t < NBLK) ? hist[b * NBLK + t] : 0;
    buf[t] = x;
    __syncthreads();
    for (int d = 1; d < 512; d <<= 1) {
        const int y = (t >= d) ? buf[t - d] : 0;
        __syncthreads();
        buf[t] += y;
        __syncthreads();
    }
    if (t < NBLK) offs[t * nbuck + b] = buf[t] - x;   // bucket-relative
    if (t == 511) tot[b] = buf[511];                  // bucket total
}

// Cross-bucket exclusive scan (block 0 = users, 1 = items).
__global__ __launch_bounds__(512) void scan_buckets(
    const int* __restrict__ tot_u, int* __restrict__ bbase_u,
    const int* __restrict__ tot_i, int* __restrict__ bbase_i)
{
    __shared__ int buf[512];
    const int t = threadIdx.x;
    const int* tot; int* bbase; int nb;
    if (blockIdx.x == 0) { tot = tot_u; bbase = bbase_u; nb = NBUCK_U; }
    else                 { tot = tot_i; bbase = bbase_i; nb = NBUCK_I; }
    const int v = (t < nb) ? tot[t] : 0;
    buf[t] = v;
    __syncthreads();
    for (int d = 1; d < 512; d <<= 1) {
        const int y = (t >= d) ? buf[t - d] : 0;
        __syncthreads();
        buf[t] += y;
        __syncthreads();
    }
    if (t <= nb) bbase[t] = buf[t] - v;   // exclusive; bbase[nb] = total
}

// LDS-staged scatter: per block, sort the 4096 edges by bucket in LDS, then
// dump bucket runs contiguously (consecutive threads -> consecutive global
// addresses). Two phases (U then I) reuse the same LDS.
// u stage: col(16b) | local_row(8b)<<16 ; i stage: row(17b) | local_col(8b)<<17.
__global__ __launch_bounds__(512) void msplit_scatter(
    const int* __restrict__ rows, const int* __restrict__ cols,
    const float* __restrict__ vals,
    const int* __restrict__ offs_u, const int* __restrict__ offs_i,
    const int* __restrict__ bbase_u, const int* __restrict__ bbase_i,
    int2* __restrict__ stage_u, int2* __restrict__ stage_i)
{
    __shared__ int buf[512];                 // hist -> inclusive scan
    __shared__ int cur[512];                 // LDS cursors
    __shared__ int gb[512];                  // run_base - local_excl per bucket
    __shared__ int ed0[EPB], ed1[EPB];       // staged entries (32KB)
    __shared__ unsigned short bpos[EPB];     // bucket of each LDS slot (8KB)
    const int t = threadIdx.x;
    const int base = blockIdx.x * EPB;
    const int end = min(base + EPB, NNZ_COUNT);
    const int n = end - base;

    // ================= U phase (key = row >> 8) =================
    buf[t] = 0;
    __syncthreads();
    for (int e = base + t; e < end; e += 512)
        atomicAdd(&buf[rows[e] >> 8], 1);
    __syncthreads();
    int x = buf[t];
    __syncthreads();
    {   // in-place inclusive scan (re-init to guarantee clean state)
        buf[t] = x;
        __syncthreads();
        for (int d = 1; d < 512; d <<= 1) {
            const int y = (t >= d) ? buf[t - d] : 0;
            __syncthreads();
            buf[t] += y;
            __syncthreads();
        }
    }
    {
        const int excl = buf[t] - x;
        cur[t] = excl;
        if (t < NBUCK_U)
            gb[t] = offs_u[blockIdx.x * NBUCK_U + t] + bbase_u[t] - excl;
    }
    __syncthreads();
    for (int e = base + t; e < end; e += 512) {
        const int r = rows[e];
        const int b = r >> 8;
        const int pos = atomicAdd(&cur[b], 1);
        ed0[pos] = cols[e] | ((r & 255) << 16);
        ed1[pos] = __float_as_int(vals[e]);
        bpos[pos] = (unsigned short)b;
    }
    __syncthreads();
    for (int k = t; k < n; k += 512)
        stage_u[gb[bpos[k]] + k] = make_int2(ed0[k], ed1[k]);
    __syncthreads();

    // ================= I phase (key = col >> 8) =================
    buf[t] = 0;
    __syncthreads();
    for (int e = base + t; e < end; e += 512)
        atomicAdd(&buf[cols[e] >> 8], 1);
    __syncthreads();
    x = buf[t];
    __syncthreads();
    {
        buf[t] = x;
        __syncthreads();
        for (int d = 1; d < 512; d <<= 1) {
            const int y = (t >= d) ? buf[t - d] : 0;
            __syncthreads();
            buf[t] += y;
            __syncthreads();
        }
    }
    {
        const int excl = buf[t] - x;
        cur[t] = excl;
        if (t < NBUCK_I)
            gb[t] = offs_i[blockIdx.x * NBUCK_I + t] + bbase_i[t] - excl;
    }
    __syncthreads();
    for (int e = base + t; e < end; e += 512) {
        const int c = cols[e];
        const int b = c >> 8;
        const int pos = atomicAdd(&cur[b], 1);
        ed0[pos] = rows[e] | ((c & 255) << 17);
        ed1[pos] = __float_as_int(vals[e]);
        bpos[pos] = (unsigned short)b;
    }
    __syncthreads();
    for (int k = t; k < n; k += 512)
        stage_i[gb[bpos[k]] + k] = make_int2(ed0[k], ed1[k]);
}

// Phase B: one block per bucket. LDS histogram of the bucket's 256 local
// rows -> LDS scan -> per-row CSR pointers written inline -> LDS-staged
// row-sort of the packed 4B pairs -> COALESCED contiguous dump.
//   u pair: col(16b) | bf16(val)<<16
//   i pair: row(17b) | (bf16(val)&0x7FFF)<<17   (val >= 0, sign dropped)
__global__ __launch_bounds__(256) void bucket_build(
    const int* __restrict__ bbase_u, const int2* __restrict__ stage_u,
    unsigned* __restrict__ pairs_u, int* __restrict__ ptr_u,
    const int* __restrict__ bbase_i, const int2* __restrict__ stage_i,
    unsigned* __restrict__ pairs_i, int* __restrict__ ptr_i)
{
    __shared__ int hcnt[256];
    __shared__ int buf[256];
    __shared__ int cur[256];
    __shared__ unsigned plds[BCAP];          // 48KB staging
    const int t = threadIdx.x;
    int b = blockIdx.x;
    const bool uside = (b < NBUCK_U);
    const int* bbase; const int2* stage; unsigned* pairs; int* ptr; int n; int sh;
    if (uside) { bbase = bbase_u; stage = stage_u; pairs = pairs_u; ptr = ptr_u; n = NUM_USERS; sh = 16; }
    else { b -= NBUCK_U; bbase = bbase_i; stage = stage_i; pairs = pairs_i; ptr = ptr_i; n = NUM_ITEMS; sh = 17; }
    const int beg = bbase[b];
    const int end = bbase[b + 1];
    const int cnt = end - beg;

    hcnt[t] = 0;
    __syncthreads();
    for (int idx = beg + t; idx < end; idx += 256)
        atomicAdd(&hcnt[(stage[idx].x >> sh) & 255], 1);
    __syncthreads();

    const int v = hcnt[t];
    buf[t] = v;
    __syncthreads();
    for (int d = 1; d < 256; d <<= 1) {
        const int y = (t >= d) ? buf[t - d] : 0;
        __syncthreads();
        buf[t] += y;
        __syncthreads();
    }
    const int excl = buf[t] - v;
    const int rowbase = beg + excl;          // bucket base + exclusive scan
    const int first = b << 8;
    if (first + t < n) ptr[first + t] = rowbase;
    if (first + t == n) ptr[n] = end;                       // partial last bucket
    else if (first + 256 == n && t == 0) ptr[n] = end;      // exact-fit last bucket

    if (cnt <= BCAP) {
        // LDS-staged: sort by local row into plds, then coalesced dump.
        cur[t] = excl;
        __syncthreads();
        for (int idx = beg + t; idx < end; idx += 256) {
            const int2 s = stage[idx];
            const int local = (s.x >> sh) & 255;
            const unsigned vb = bf16_rnd(__int_as_float(s.y));
            unsigned packed;
            if (uside) packed = (unsigned)(s.x & 0xFFFF) | (vb << 16);
            else       packed = (unsigned)(s.x & 0x1FFFF) | ((vb & 0x7FFFu) << 17);
            const int slot = atomicAdd(&cur[local], 1);
            plds[slot] = packed;
        }
        __syncthreads();
        for (int k = t; k < cnt; k += 256)
            pairs[beg + k] = plds[k];
    } else {
        // fallback: direct scatter (safety for improbable oversize bucket)
        cur[t] = rowbase;
        __syncthreads();
        for (int idx = beg + t; idx < end; idx += 256) {
            const int2 s = stage[idx];
            const int local = (s.x >> sh) & 255;
            const unsigned vb = bf16_rnd(__int_as_float(s.y));
            unsigned packed;
            if (uside) packed = (unsigned)(s.x & 0xFFFF) | (vb << 16);
            else       packed = (unsigned)(s.x & 0x1FFFF) | ((vb & 0x7FFFu) << 17);
            const int slot = atomicAdd(&cur[local], 1);
            pairs[slot] = packed;
        }
    }
}

// ---------------- SpMM: one 64-lane wave per destination row ----------------

template<bool USIDE>
__device__ __forceinline__ void decode_pair(unsigned s, int& c, float& v) {
    if (USIDE) { c = (int)(s & 0xFFFFu);  v = __uint_as_float(s & 0xFFFF0000u); }
    else       { c = (int)(s & 0x1FFFFu); v = __uint_as_float((s & 0xFFFE0000u) >> 1); }
}

// MODE 0: write bf16 dst only. MODE 1: out = (base + l1 + l2 + acc) * 0.25.
template<int MODE, bool USIDE>
__device__ __forceinline__ void spmm_row_bf(
    const int* __restrict__ ptr, const unsigned* __restrict__ pairs,
    const unsigned* __restrict__ src, unsigned* __restrict__ dst,
    const unsigned* __restrict__ l1, const unsigned* __restrict__ l2,
    const float* __restrict__ base, float* __restrict__ out,
    int row, int lane)
{
    const int start = __builtin_amdgcn_readfirstlane(ptr[row]);
    const int end   = __builtin_amdgcn_readfirstlane(ptr[row + 1]);
    const unsigned* __restrict__ srcl = src + lane;   // gather = srcl[c * 64]
    v2f acc; acc.x = 0.f; acc.y = 0.f;

    int e = start;
    for (; e + 16 <= end; e += 16) {
        unsigned s[16]; int c[16]; float v[16]; unsigned g[16];
        #pragma unroll
        for (int k = 0; k < 16; ++k) s[k] = pairs[e + k];   // uniform addr
        #pragma unroll
        for (int k = 0; k < 16; ++k) {
            decode_pair<USIDE>(s[k], c[k], v[k]);
            g[k] = srcl[(size_t)c[k] * 64];
        }
        #pragma unroll
        for (int k = 0; k < 16; ++k) {
            v2f gv; gv.x = __uint_as_float(g[k] << 16);
            gv.y = __uint_as_float(g[k] & 0xFFFF0000u);
            acc += v[k] * gv;                               // v_pk_fma_f32
        }
    }
    for (; e + 8 <= end; e += 8) {
        unsigned s[8]; int c[8]; float v[8]; unsigned g[8];
        #pragma unroll
        for (int k = 0; k < 8; ++k) s[k] = pairs[e + k];
        #pragma unroll
        for (int k = 0; k < 8; ++k) {
            decode_pair<USIDE>(s[k], c[k], v[k]);
            g[k] = srcl[(size_t)c[k] * 64];
        }
        #pragma unroll
        for (int k = 0; k < 8; ++k) {
            v2f gv; gv.x = __uint_as_float(g[k] << 16);
            gv.y = __uint_as_float(g[k] & 0xFFFF0000u);
            acc += v[k] * gv;
        }
    }
    for (; e < end; ++e) {
        const unsigned s = pairs[e];
        int c; float v;
        decode_pair<USIDE>(s, c, v);
        const unsigned g = srcl[(size_t)c * 64];
        v2f gv; gv.x = __uint_as_float(g << 16);
        gv.y = __uint_as_float(g & 0xFFFF0000u);
        acc += v * gv;
    }

    if (MODE == 0) {
        __builtin_nontemporal_store(pack_bf16(acc.x, acc.y),
                                    dst + (size_t)row * 64 + lane);
    } else {
        const unsigned a1 = __builtin_nontemporal_load(l1 + (size_t)row * 64 + lane);
        const unsigned a2 = __builtin_nontemporal_load(l2 + (size_t)row * 64 + lane);
        const size_t o = (size_t)row * EMBED_DIM + (lane << 1);
        const v2f bs = __builtin_nontemporal_load(
            reinterpret_cast<const v2f*>(base + o));
        v2f r;
        r.x = (bs.x + __uint_as_float(a1 << 16) + __uint_as_float(a2 << 16) + acc.x) * 0.25f;
        r.y = (bs.y + __uint_as_float(a1 & 0xFFFF0000u) + __uint_as_float(a2 & 0xFFFF0000u) + acc.y) * 0.25f;
        __builtin_nontemporal_store(r, reinterpret_cast<v2f*>(out + o));
    }
}

template<int MODE>
__global__ __launch_bounds__(256) void csr_spmm_dual_bf(
    const int* __restrict__ ptr_u, const unsigned* __restrict__ pairs_u,
    const unsigned* __restrict__ src_u, unsigned* __restrict__ dst_u,
    const unsigned* __restrict__ l1_u, const unsigned* __restrict__ l2_u,
    const float* __restrict__ base_u, float* __restrict__ out_u,
    const int* __restrict__ ptr_i, const unsigned* __restrict__ pairs_i,
    const unsigned* __restrict__ src_i, unsigned* __restrict__ dst_i,
    const unsigned* __restrict__ l1_i, const unsigned* __restrict__ l2_i,
    const float* __restrict__ base_i, float* __restrict__ out_i,
    int GU)
{
    const int lane = threadIdx.x & 63;
    const int w = threadIdx.x >> 6;
    if ((int)blockIdx.x < GU) {
        const int row = blockIdx.x * 4 + w;
        if (row < NUM_USERS)
            spmm_row_bf<MODE, true>(ptr_u, pairs_u, src_u, dst_u, l1_u, l2_u, base_u, out_u, row, lane);
    } else {
        const int row = ((int)blockIdx.x - GU) * 4 + w;
        if (row < NUM_ITEMS)
            spmm_row_bf<MODE, false>(ptr_i, pairs_i, src_i, dst_i, l1_i, l2_i, base_i, out_i, row, lane);
    }
}

// ---------------- fallback (round-1 atomic path) ----------------

__global__ __launch_bounds__(256) void edge_spmm(
    const float* __restrict__ vals, const int* __restrict__ rows,
    const int* __restrict__ cols, const float* __restrict__ u_src,
    const float* __restrict__ i_src, float* __restrict__ u_dst,
    float* __restrict__ i_dst, int nnz)
{
    const int lane = threadIdx.x & 31;
    const int e = blockIdx.x * 8 + (threadIdx.x >> 5);
    if (e >= nnz) return;
    const float v = vals[e];
    const size_t ro = (size_t)rows[e] * EMBED_DIM + lane * 4;
    const size_t co = (size_t)cols[e] * EMBED_DIM + lane * 4;
    const float4 iv = *reinterpret_cast<const float4*>(i_src + co);
    const float4 uv = *reinterpret_cast<const float4*>(u_src + ro);
    atomicAdd(u_dst + ro + 0, v * iv.x); atomicAdd(u_dst + ro + 1, v * iv.y);
    atomicAdd(u_dst + ro + 2, v * iv.z); atomicAdd(u_dst + ro + 3, v * iv.w);
    atomicAdd(i_dst + co + 0, v * uv.x); atomicAdd(i_dst + co + 1, v * uv.y);
    atomicAdd(i_dst + co + 2, v * uv.z); atomicAdd(i_dst + co + 3, v * uv.w);
}

__global__ __launch_bounds__(256) void acc_scale(
    float* __restrict__ out, const float* __restrict__ x, long n, float scale)
{
    long i = ((long)blockIdx.x * blockDim.x + threadIdx.x) * 4;
    if (i >= n) return;
    float4 o = *reinterpret_cast<float4*>(out + i);
    float4 a = *reinterpret_cast<const float4*>(x + i);
    o.x = (o.x + a.x) * scale; o.y = (o.y + a.y) * scale;
    o.z = (o.z + a.z) * scale; o.w = (o.w + a.w) * scale;
    *reinterpret_cast<float4*>(out + i) = o;
}

// ---------------- launch ----------------

extern "C" void kernel_launch(void* const* d_in, const int* in_sizes, int n_in,
                              void* d_out, int out_size, void* d_ws, size_t ws_size,
                              hipStream_t stream)
{
    const float* user = (const float*)d_in[0];
    const float* item = (const float*)d_in[1];
    const float* vals = (const float*)d_in[2];
    const int*   rows = (const int*)d_in[3];
    const int*   cols = (const int*)d_in[4];

    const size_t UD = (size_t)NUM_USERS * EMBED_DIM;   // 12.8M
    const size_t ID = (size_t)NUM_ITEMS * EMBED_DIM;   //  6.4M

    float* out_u = (float*)d_out;
    float* out_i = out_u + UD;

    // ---- CSR-path workspace layout ----
    char* ws = (char*)d_ws;
    unsigned* user_bf = (unsigned*)ws;              ws += UD * 2;
    unsigned* item_bf = (unsigned*)ws;              ws += ID * 2;
    unsigned* uA = (unsigned*)ws;                   ws += UD * 2;
    unsigned* uB = (unsigned*)ws;                   ws += UD * 2;
    unsigned* iA = (unsigned*)ws;                   ws += ID * 2;
    unsigned* iB = (unsigned*)ws;                   ws += ID * 2;
    unsigned* pairs_u = (unsigned*)ws;              ws += (size_t)NNZ_COUNT * 4;
    unsigned* pairs_i = (unsigned*)ws;              ws += (size_t)NNZ_COUNT * 4;
    int2* stage_u = (int2*)ws;                      ws += (size_t)NNZ_COUNT * 8;
    int2* stage_i = (int2*)ws;                      ws += (size_t)NNZ_COUNT * 8;
    int* ptr_u = (int*)ws;                          ws += (NUM_USERS + 1) * 4;
    int* ptr_i = (int*)ws;                          ws += (NUM_ITEMS + 1) * 4;
    int* bbase_u = (int*)ws;                        ws += (NBUCK_U + 1) * 4;
    int* bbase_i = (int*)ws;                        ws += (NBUCK_I + 1) * 4;
    const size_t REQ = (size_t)(ws - (char*)d_ws);  // ~164 MB

    // hist/offs/tot (~2.3 MB at NBLK=489) alias into pairs_u: all consumed
    // by msplit_offsets/scan_buckets/msplit_scatter before bucket_build ever
    // writes pairs_u (disjoint lifetimes). bbase is NOT aliased.
    int* hist_u = (int*)pairs_u;
    int* hist_i = hist_u + NBUCK_U * NBLK;
    int* offs_u = hist_i + NBUCK_I * NBLK;
    int* offs_i = offs_u + NBLK * NBUCK_U;
    int* tot_u  = offs_i + NBLK * NBUCK_I;
    int* tot_i  = tot_u + NBUCK_U;

    if (ws_size >= REQ) {
        // ---- prep: bf16 copies of the input tables ----
        const int NA8 = (int)(UD / 8), NB8 = (int)(ID / 8);
        to_bf16_dual<<<(NA8 + NB8 + 255) / 256, 256, 0, stream>>>(
            user, user_bf, NA8, item, item_bf, NB8);

        // ---- atomic-free CSR build (LDS-staged, coalesced writes) ----
        msplit_hist<<<NBLK, 256, 0, stream>>>(rows, cols, hist_u, hist_i);
        msplit_offsets<<<NBUCK_U + NBUCK_I, 512, 0, stream>>>(
            hist_u, hist_i, offs_u, offs_i, tot_u, tot_i);
        scan_buckets<<<2, 512, 0, stream>>>(tot_u, bbase_u, tot_i, bbase_i);
        msplit_scatter<<<NBLK, 512, 0, stream>>>(
            rows, cols, vals, offs_u, offs_i, bbase_u, bbase_i, stage_u, stage_i);
        bucket_build<<<NBUCK_U + NBUCK_I, 256, 0, stream>>>(
            bbase_u, stage_u, pairs_u, ptr_u,
            bbase_i, stage_i, pairs_i, ptr_i);

        const int GU = (NUM_USERS + 3) / 4;   // 25000
        const int GI = (NUM_ITEMS + 3) / 4;   // 12500

        // layer 1: src = bf16 inputs -> uA/iA (dst only, no sum traffic)
        csr_spmm_dual_bf<0><<<GU + GI, 256, 0, stream>>>(
            ptr_u, pairs_u, item_bf, uA, nullptr, nullptr, nullptr, nullptr,
            ptr_i, pairs_i, user_bf, iA, nullptr, nullptr, nullptr, nullptr, GU);
        // layer 2: src = uA/iA -> uB/iB
        csr_spmm_dual_bf<0><<<GU + GI, 256, 0, stream>>>(
            ptr_u, pairs_u, iA, uB, nullptr, nullptr, nullptr, nullptr,
            ptr_i, pairs_i, uA, iB, nullptr, nullptr, nullptr, nullptr, GU);
        // layer 3: fused epilogue out = (base + l1 + l2 + acc) / 4
        csr_spmm_dual_bf<1><<<GU + GI, 256, 0, stream>>>(
            ptr_u, pairs_u, iB, nullptr, uA, uB, user, out_u,
            ptr_i, pairs_i, uB, nullptr, iA, iB, item, out_i, GU);
    } else {
        // ---- fallback: round-1 atomic path (fp32 buffers carved from ws) ----
        char* fw = (char*)d_ws;
        float* fuA = (float*)fw;                    fw += UD * 4;
        float* fuB = (float*)fw;                    fw += UD * 4;
        float* fiA = (float*)fw;                    fw += ID * 4;
        float* fiB = (float*)fw;                    fw += ID * 4;

        const int EDGE_BLOCKS = (NNZ_COUNT + 7) / 8;
        const int ACC_U = (int)(UD / 1024), ACC_I = (int)(ID / 1024);

        hipMemcpyAsync(out_u, user, UD * 4, hipMemcpyDeviceToDevice, stream);
        hipMemcpyAsync(out_i, item, ID * 4, hipMemcpyDeviceToDevice, stream);

        hipMemsetAsync(fuA, 0, UD * 4, stream);
        hipMemsetAsync(fiA, 0, ID * 4, stream);
        edge_spmm<<<EDGE_BLOCKS, 256, 0, stream>>>(vals, rows, cols, user, item, fuA, fiA, NNZ_COUNT);
        acc_scale<<<ACC_U, 256, 0, stream>>>(out_u, fuA, (long)UD, 1.0f);
        acc_scale<<<ACC_I, 256, 0, stream>>>(out_i, fiA, (long)ID, 1.0f);

        hipMemsetAsync(fuB, 0, UD * 4, stream);
        hipMemsetAsync(fiB, 0, ID * 4, stream);
        edge_spmm<<<EDGE_BLOCKS, 256, 0, stream>>>(vals, rows, cols, fuA, fiA, fuB, fiB, NNZ_COUNT);
        acc_scale<<<ACC_U, 256, 0, stream>>>(out_u, fuB, (long)UD, 1.0f);
        acc_scale<<<ACC_I, 256, 0, stream>>>(out_i, fiB, (long)ID, 1.0f);

        hipMemsetAsync(fuA, 0, UD * 4, stream);
        hipMemsetAsync(fiA, 0, ID * 4, stream);
        edge_spmm<<<EDGE_BLOCKS, 256, 0, stream>>>(vals, rows, cols, fuB, fiB, fuA, fiA, NNZ_COUNT);
        acc_scale<<<ACC_U, 256, 0, stream>>>(out_u, fuA, (long)UD, 0.25f);
        acc_scale<<<ACC_I, 256, 0, stream>>>(out_i, fiA, (long)ID, 0.25f);
    }
}